// Round 3
// baseline (1075.470 us; speedup 1.0000x reference)
//
#include <hip/hip_runtime.h>
#include <math.h>

// Problem constants
#define NTOT   65536
#define NPG    1024
#define NGRAPH 64
#define KNN    8
#define HDIM   128
#define XSTR   33     // x row stride (32 feat + 1 kf)
#define NEG    0.2f

typedef _Float16 h2 __attribute__((ext_vector_type(2)));
typedef _Float16 h8 __attribute__((ext_vector_type(8)));

#if defined(__has_builtin)
#if __has_builtin(__builtin_amdgcn_fdot2)
#define HAVE_FDOT2 1
#endif
#endif

__device__ __forceinline__ float fdot2f(h2 a, h2 b, float c) {
#ifdef HAVE_FDOT2
  return __builtin_amdgcn_fdot2(a, b, c, false);
#else
  return c + (float)a.x * (float)b.x + (float)a.y * (float)b.y;
#endif
}

// ---------------------------------------------------------------------------
// K0: xh = relu(feat @ w0 + b0); sq[n] = sum(xh[n]^2)
// grid 2048 x 256 threads; 32 nodes/block
// ---------------------------------------------------------------------------
__global__ __launch_bounds__(256) void k_embed(const float* __restrict__ x,
                                               const float* __restrict__ w0,
                                               const float* __restrict__ b0,
                                               float* __restrict__ xh,
                                               float* __restrict__ sq) {
  __shared__ float w0s[32 * HDIM];
  __shared__ float fs[2][32];
  __shared__ float red[256];
  const int tid = threadIdx.x;
  for (int i = tid; i < 32 * HDIM; i += 256) w0s[i] = w0[i];
  const int h = tid & 127;
  const int nl = tid >> 7;  // 0/1
  const float bias = b0[h];
  for (int it = 0; it < 16; ++it) {
    const int n = blockIdx.x * 32 + it * 2 + nl;
    __syncthreads();  // protects w0s (1st iter) and fs/red reuse
    if (tid < 64) {
      const int r = tid >> 5, f = tid & 31;
      fs[r][f] = x[(size_t)(blockIdx.x * 32 + it * 2 + r) * XSTR + f];
    }
    __syncthreads();
    float acc = bias;
#pragma unroll
    for (int f = 0; f < 32; ++f) acc = fmaf(fs[nl][f], w0s[f * HDIM + h], acc);
    acc = fmaxf(acc, 0.f);
    xh[(size_t)n * HDIM + h] = acc;
    red[tid] = acc * acc;
    __syncthreads();
    for (int s = 64; s > 0; s >>= 1) {
      if ((tid & 127) < s) red[tid] += red[tid + s];
      __syncthreads();
    }
    if ((tid & 127) == 0) sq[n] = red[tid];
  }
}

// ---------------------------------------------------------------------------
// K1: per-graph kNN (k=8, exclude self, tie -> lowest index).
// grid 512 (64 graphs x 8 row-tiles of 128), 256 threads.
// fp32 GEMM 128x64 tiles, K=128 in chunks of 32; top-8 via 2 threads/row.
// ---------------------------------------------------------------------------
__global__ __launch_bounds__(256) void k_knn(const float* __restrict__ xh,
                                             const float* __restrict__ sq,
                                             int* __restrict__ nbr) {
  // float layout: As[32][132] | Bs[32][68] | sqs[64] | Ds[128][65]
  __shared__ __align__(16) float smem[14784];
  float* As = smem;
  float* Bs = smem + 4224;
  float* sqs = smem + 6400;
  float* Ds = smem + 6464;

  const int tid = threadIdx.x;
  const int g = blockIdx.x >> 3;
  const int n0 = (blockIdx.x & 7) * 128;
  const int gbase = g * NPG;
  const int ty = tid >> 4, tx = tid & 15;
  const int row = tid >> 1, half = tid & 1;
  const int nglob = gbase + n0 + row;
  const float sqn = sq[nglob];

  float bd[8];
  int bi[8];
#pragma unroll
  for (int i = 0; i < 8; ++i) { bd[i] = 1e30f; bi[i] = 0; }

  for (int mt = 0; mt < 16; ++mt) {
    const int m0 = gbase + mt * 64;
    float acc[8][4];
#pragma unroll
    for (int r = 0; r < 8; ++r)
#pragma unroll
      for (int c = 0; c < 4; ++c) acc[r][c] = 0.f;
    __syncthreads();  // previous tile's scan done (sqs/Ds safe to rewrite)
    if (tid < 64) sqs[tid] = sq[m0 + tid];
    for (int kc = 0; kc < HDIM; kc += 32) {
#pragma unroll
      for (int i = 0; i < 4; ++i) {
        const int s = tid + i * 256;
        const int r = s >> 3, kq = s & 7;
        const float4 v = *reinterpret_cast<const float4*>(
            &xh[(size_t)(gbase + n0 + r) * HDIM + kc + kq * 4]);
        As[(kq * 4 + 0) * 132 + r] = v.x;
        As[(kq * 4 + 1) * 132 + r] = v.y;
        As[(kq * 4 + 2) * 132 + r] = v.z;
        As[(kq * 4 + 3) * 132 + r] = v.w;
      }
#pragma unroll
      for (int i = 0; i < 2; ++i) {
        const int s = tid + i * 256;
        const int c = s >> 3, kq = s & 7;
        const float4 v = *reinterpret_cast<const float4*>(
            &xh[(size_t)(m0 + c) * HDIM + kc + kq * 4]);
        Bs[(kq * 4 + 0) * 68 + c] = v.x;
        Bs[(kq * 4 + 1) * 68 + c] = v.y;
        Bs[(kq * 4 + 2) * 68 + c] = v.z;
        Bs[(kq * 4 + 3) * 68 + c] = v.w;
      }
      __syncthreads();
      for (int kk = 0; kk < 32; ++kk) {
        const float4 a0 = *reinterpret_cast<const float4*>(&As[kk * 132 + ty * 8]);
        const float4 a1 = *reinterpret_cast<const float4*>(&As[kk * 132 + ty * 8 + 4]);
        const float4 b0 = *reinterpret_cast<const float4*>(&Bs[kk * 68 + tx * 4]);
        const float av[8] = {a0.x, a0.y, a0.z, a0.w, a1.x, a1.y, a1.z, a1.w};
        const float bv[4] = {b0.x, b0.y, b0.z, b0.w};
#pragma unroll
        for (int r = 0; r < 8; ++r)
#pragma unroll
          for (int c = 0; c < 4; ++c) acc[r][c] = fmaf(av[r], bv[c], acc[r][c]);
      }
      __syncthreads();
    }
#pragma unroll
    for (int r = 0; r < 8; ++r)
#pragma unroll
      for (int c = 0; c < 4; ++c) Ds[(ty * 8 + r) * 65 + tx * 4 + c] = acc[r][c];
    __syncthreads();
    // scan this tile: thread (row, half) scans 32 columns, m increasing
    for (int c2 = 0; c2 < 32; ++c2) {
      const int c = half * 32 + c2;
      const int m = m0 + c;
      const float d = sqn + sqs[c] - 2.f * Ds[row * 65 + c];
      if ((m != nglob) && (d < bd[7])) {   // strict <: ties keep earlier (lower) m
        bd[7] = d; bi[7] = m;
#pragma unroll
        for (int q = 7; q > 0; --q) {
          if (bd[q] < bd[q - 1]) {         // strict: stable w.r.t. equals
            const float td = bd[q]; bd[q] = bd[q - 1]; bd[q - 1] = td;
            const int ti = bi[q]; bi[q] = bi[q - 1]; bi[q - 1] = ti;
          }
        }
      }
    }
  }
  __syncthreads();
  // merge the two half-lists per row (tie -> lower index, matching jax top_k)
  float* mdist = smem;                        // 256*8 floats
  int* midx = reinterpret_cast<int*>(smem + 2048);
#pragma unroll
  for (int i = 0; i < 8; ++i) { mdist[tid * 8 + i] = bd[i]; midx[tid * 8 + i] = bi[i]; }
  __syncthreads();
  if (half == 0) {
    const float* dA = &mdist[(row * 2) * 8];
    const float* dB = &mdist[(row * 2 + 1) * 8];
    const int* iA = &midx[(row * 2) * 8];
    const int* iB = &midx[(row * 2 + 1) * 8];
    int pa = 0, pb = 0;
    int* outp = &nbr[(size_t)nglob * KNN];
#pragma unroll
    for (int i = 0; i < 8; ++i) {
      const float da = dA[pa], db = dB[pb];
      const bool takeA = (da < db) || ((da == db) && (iA[pa] < iB[pb]));
      outp[i] = takeA ? iA[pa] : iB[pb];
      if (takeA) ++pa; else ++pb;
    }
  }
}

// ---------------------------------------------------------------------------
// K2: node-level GEMMs: out = xin @ W (+bias), fp16 output. blockIdx.y selects
// {a1 = x@mw1[:128]+mb1, a2 = x@mw1[128:256], u = x@gw[:128]+gb, v = x@gw[128:256]}
// grid (512,4) x 256 threads; 128x128 tile, K=128 in chunks of 32, 8x8/thread.
// ---------------------------------------------------------------------------
__global__ __launch_bounds__(256) void k_nodegemm(const float* __restrict__ xin,
                                                  const float* __restrict__ mw1,
                                                  const float* __restrict__ gw,
                                                  const float* __restrict__ mb1,
                                                  const float* __restrict__ gb,
                                                  _Float16* __restrict__ a1,
                                                  _Float16* __restrict__ a2,
                                                  _Float16* __restrict__ uu,
                                                  _Float16* __restrict__ vv) {
  __shared__ __align__(16) float As[32][132];
  __shared__ __align__(16) float Bs[32][132];
  const int tid = threadIdx.x;
  const int n0 = blockIdx.x * 128;
  const int cb = blockIdx.y;
  const float* W = (cb == 0) ? mw1 : (cb == 1) ? (mw1 + 128 * HDIM)
                 : (cb == 2) ? gw : (gw + 128 * HDIM);
  const float* bias = (cb == 0) ? mb1 : (cb == 2) ? gb : nullptr;
  _Float16* outp = (cb == 0) ? a1 : (cb == 1) ? a2 : (cb == 2) ? uu : vv;
  const int ty = tid >> 4, tx = tid & 15;
  float acc[8][8];
#pragma unroll
  for (int r = 0; r < 8; ++r)
#pragma unroll
    for (int c = 0; c < 8; ++c) acc[r][c] = 0.f;
  for (int kc = 0; kc < HDIM; kc += 32) {
#pragma unroll
    for (int i = 0; i < 4; ++i) {
      const int s = tid + i * 256;
      const int r = s >> 3, kq = s & 7;
      const float4 v = *reinterpret_cast<const float4*>(
          &xin[(size_t)(n0 + r) * HDIM + kc + kq * 4]);
      As[kq * 4 + 0][r] = v.x;
      As[kq * 4 + 1][r] = v.y;
      As[kq * 4 + 2][r] = v.z;
      As[kq * 4 + 3][r] = v.w;
    }
#pragma unroll
    for (int i = 0; i < 4; ++i) {
      const int s = tid + i * 256;
      const int kk = s >> 5, c4 = s & 31;
      const float4 v = *reinterpret_cast<const float4*>(
          &W[(size_t)(kc + kk) * HDIM + c4 * 4]);
      *reinterpret_cast<float4*>(&Bs[kk][c4 * 4]) = v;
    }
    __syncthreads();
    for (int kk = 0; kk < 32; ++kk) {
      const float4 a0 = *reinterpret_cast<const float4*>(&As[kk][ty * 8]);
      const float4 a1v = *reinterpret_cast<const float4*>(&As[kk][ty * 8 + 4]);
      const float4 b0 = *reinterpret_cast<const float4*>(&Bs[kk][tx * 8]);
      const float4 b1 = *reinterpret_cast<const float4*>(&Bs[kk][tx * 8 + 4]);
      const float av[8] = {a0.x, a0.y, a0.z, a0.w, a1v.x, a1v.y, a1v.z, a1v.w};
      const float bv[8] = {b0.x, b0.y, b0.z, b0.w, b1.x, b1.y, b1.z, b1.w};
#pragma unroll
      for (int r = 0; r < 8; ++r)
#pragma unroll
        for (int c = 0; c < 8; ++c) acc[r][c] = fmaf(av[r], bv[c], acc[r][c]);
    }
    __syncthreads();
  }
  float bv[8];
#pragma unroll
  for (int c = 0; c < 8; ++c) bv[c] = bias ? bias[tx * 8 + c] : 0.f;
#pragma unroll
  for (int r = 0; r < 8; ++r) {
    h8 o;
#pragma unroll
    for (int c = 0; c < 8; ++c) o[c] = (_Float16)(acc[r][c] + bv[c]);
    *reinterpret_cast<h8*>(&outp[(size_t)(n0 + ty * 8 + r) * HDIM + tx * 8]) = o;
  }
}

// ---------------------------------------------------------------------------
// K3: fused highway edge conv. 16 nodes (128 edges)/block, 256 threads.
// E = relu(a1[i]+a2[j]+fd*w1r) staged f16-paired in LDS; M = E@mw2 (fdot2);
// epilogue: gate sigmoid, msg mean, +x skip, leaky_relu.
// grid 4096 x 256.
// ---------------------------------------------------------------------------
__global__ __launch_bounds__(256) void k_conv(const float* __restrict__ xin,
                                              const int* __restrict__ nbr,
                                              const float* __restrict__ xraw,
                                              const _Float16* __restrict__ a1,
                                              const _Float16* __restrict__ a2,
                                              const _Float16* __restrict__ uu,
                                              const _Float16* __restrict__ vv,
                                              const float* __restrict__ mw1,
                                              const float* __restrict__ mw2,
                                              const float* __restrict__ mb2,
                                              const float* __restrict__ gw,
                                              float* __restrict__ xout) {
  __shared__ __align__(16) h2 Et[64][128];   // [k2][edge] pairs (E[e][2k2],E[e][2k2+1])
  __shared__ __align__(16) h2 Ws[64][128];   // [k2][h]   pairs (mw2[2k2][h],mw2[2k2+1][h])
  __shared__ int jn[128];
  __shared__ float fdv[128];
  __shared__ float w1rs[HDIM];
  __shared__ float gwrs[HDIM];
  const int tid = threadIdx.x;
  const int i0 = blockIdx.x * 16;

  if (tid < 128) {
    w1rs[tid] = mw1[256 * HDIM + tid];
    gwrs[tid] = gw[256 * HDIM + tid];
    const int i = i0 + (tid >> 3);
    const int j = nbr[(size_t)i * KNN + (tid & 7)];
    jn[tid] = j;
    fdv[tid] = xraw[(size_t)i * XSTR + 32] - xraw[(size_t)j * XSTR + 32];
  }
  // stage mw2 as f16 pairs
#pragma unroll
  for (int c = 0; c < 8; ++c) {
    const int s = tid + c * 256;
    const int k2 = s >> 5, h4 = s & 31;
    const float4 va = *reinterpret_cast<const float4*>(&mw2[(size_t)(2 * k2) * HDIM + h4 * 4]);
    const float4 vb = *reinterpret_cast<const float4*>(&mw2[(size_t)(2 * k2 + 1) * HDIM + h4 * 4]);
    h2 t0; t0.x = (_Float16)va.x; t0.y = (_Float16)vb.x; Ws[k2][h4 * 4 + 0] = t0;
    h2 t1; t1.x = (_Float16)va.y; t1.y = (_Float16)vb.y; Ws[k2][h4 * 4 + 1] = t1;
    h2 t2; t2.x = (_Float16)va.z; t2.y = (_Float16)vb.z; Ws[k2][h4 * 4 + 2] = t2;
    h2 t3; t3.x = (_Float16)va.w; t3.y = (_Float16)vb.w; Ws[k2][h4 * 4 + 3] = t3;
  }
  __syncthreads();
  // build E (each thread: one edge, half of the k dimension)
  {
    const int e = tid >> 1;
    const int kk0 = (tid & 1) * 64;
    const int inode = i0 + (e >> 3);
    const int j = jn[e];
    const float fd = fdv[e];
    const h8* A1p = reinterpret_cast<const h8*>(&a1[(size_t)inode * HDIM + kk0]);
    const h8* A2p = reinterpret_cast<const h8*>(&a2[(size_t)j * HDIM + kk0]);
#pragma unroll
    for (int s8 = 0; s8 < 8; ++s8) {
      const int kk = kk0 + s8 * 8;
      const h8 va = A1p[s8];
      const h8 vb = A2p[s8];
      float p[8];
#pragma unroll
      for (int q = 0; q < 8; ++q)
        p[q] = fmaxf((float)va[q] + (float)vb[q] + fd * w1rs[kk + q], 0.f);
      h2 e0; e0.x = (_Float16)p[0]; e0.y = (_Float16)p[1];
      h2 e1; e1.x = (_Float16)p[2]; e1.y = (_Float16)p[3];
      h2 e2; e2.x = (_Float16)p[4]; e2.y = (_Float16)p[5];
      h2 e3; e3.x = (_Float16)p[6]; e3.y = (_Float16)p[7];
      Et[(kk >> 1) + 0][e] = e0;
      Et[(kk >> 1) + 1][e] = e1;
      Et[(kk >> 1) + 2][e] = e2;
      Et[(kk >> 1) + 3][e] = e3;
    }
  }
  __syncthreads();
  // GEMM: M = E @ mw2 via dot2 pairs
  const int ty = tid >> 4, tx = tid & 15;  // ty = node-in-block, rows = its 8 edges
  float acc[8][8];
#pragma unroll
  for (int r = 0; r < 8; ++r)
#pragma unroll
    for (int c = 0; c < 8; ++c) acc[r][c] = 0.f;
  for (int k2 = 0; k2 < 64; ++k2) {
    const uint4 uA0 = *reinterpret_cast<const uint4*>(&Et[k2][ty * 8]);
    const uint4 uA1 = *reinterpret_cast<const uint4*>(&Et[k2][ty * 8 + 4]);
    const uint4 uB0 = *reinterpret_cast<const uint4*>(&Ws[k2][tx * 8]);
    const uint4 uB1 = *reinterpret_cast<const uint4*>(&Ws[k2][tx * 8 + 4]);
    const h2 a[8] = {__builtin_bit_cast(h2, uA0.x), __builtin_bit_cast(h2, uA0.y),
                     __builtin_bit_cast(h2, uA0.z), __builtin_bit_cast(h2, uA0.w),
                     __builtin_bit_cast(h2, uA1.x), __builtin_bit_cast(h2, uA1.y),
                     __builtin_bit_cast(h2, uA1.z), __builtin_bit_cast(h2, uA1.w)};
    const h2 b[8] = {__builtin_bit_cast(h2, uB0.x), __builtin_bit_cast(h2, uB0.y),
                     __builtin_bit_cast(h2, uB0.z), __builtin_bit_cast(h2, uB0.w),
                     __builtin_bit_cast(h2, uB1.x), __builtin_bit_cast(h2, uB1.y),
                     __builtin_bit_cast(h2, uB1.z), __builtin_bit_cast(h2, uB1.w)};
#pragma unroll
    for (int r = 0; r < 8; ++r)
#pragma unroll
      for (int c = 0; c < 8; ++c) acc[r][c] = fdot2f(a[r], b[c], acc[r][c]);
  }
  // epilogue: gate + mean + skip + leaky
  const int node = i0 + ty;
  float xi_[8], ui_[8], mb2v[8], gwv[8];
  {
    const float4 t0 = *reinterpret_cast<const float4*>(&xin[(size_t)node * HDIM + tx * 8]);
    const float4 t1 = *reinterpret_cast<const float4*>(&xin[(size_t)node * HDIM + tx * 8 + 4]);
    xi_[0] = t0.x; xi_[1] = t0.y; xi_[2] = t0.z; xi_[3] = t0.w;
    xi_[4] = t1.x; xi_[5] = t1.y; xi_[6] = t1.z; xi_[7] = t1.w;
    const h8 u8 = *reinterpret_cast<const h8*>(&uu[(size_t)node * HDIM + tx * 8]);
#pragma unroll
    for (int c = 0; c < 8; ++c) ui_[c] = (float)u8[c];
    const float4 m0 = *reinterpret_cast<const float4*>(&mb2[tx * 8]);
    const float4 m1 = *reinterpret_cast<const float4*>(&mb2[tx * 8 + 4]);
    mb2v[0] = m0.x; mb2v[1] = m0.y; mb2v[2] = m0.z; mb2v[3] = m0.w;
    mb2v[4] = m1.x; mb2v[5] = m1.y; mb2v[6] = m1.z; mb2v[7] = m1.w;
#pragma unroll
    for (int c = 0; c < 8; ++c) gwv[c] = gwrs[tx * 8 + c];
  }
  float msum[8];
#pragma unroll
  for (int c = 0; c < 8; ++c) msum[c] = 0.f;
#pragma unroll
  for (int r = 0; r < 8; ++r) {
    const int e = ty * 8 + r;
    const int j = jn[e];
    const float fd = fdv[e];
    const h8 v8 = *reinterpret_cast<const h8*>(&vv[(size_t)j * HDIM + tx * 8]);
    const float4 x0 = *reinterpret_cast<const float4*>(&xin[(size_t)j * HDIM + tx * 8]);
    const float4 x1 = *reinterpret_cast<const float4*>(&xin[(size_t)j * HDIM + tx * 8 + 4]);
    const float xj[8] = {x0.x, x0.y, x0.z, x0.w, x1.x, x1.y, x1.z, x1.w};
#pragma unroll
    for (int c = 0; c < 8; ++c) {
      const float z = ui_[c] + (float)v8[c] + fd * gwv[c];
      const float gsig = 1.f / (1.f + __expf(-z));
      const float M = acc[r][c] + mb2v[c];
      msum[c] += gsig * M + (1.f - gsig) * xj[c];
    }
  }
#pragma unroll
  for (int c = 0; c < 8; c += 4) {
    float4 o;
    float t;
    t = msum[c + 0] * 0.125f + xi_[c + 0]; o.x = (t > 0.f) ? t : NEG * t;
    t = msum[c + 1] * 0.125f + xi_[c + 1]; o.y = (t > 0.f) ? t : NEG * t;
    t = msum[c + 2] * 0.125f + xi_[c + 2]; o.z = (t > 0.f) ? t : NEG * t;
    t = msum[c + 3] * 0.125f + xi_[c + 3]; o.w = (t > 0.f) ? t : NEG * t;
    *reinterpret_cast<float4*>(&xout[(size_t)node * HDIM + tx * 8 + c]) = o;
  }
}

// ---------------------------------------------------------------------------
// K4: per-graph max-pool over [x1|x2] (256 feats), 2-layer head, log_softmax.
// grid 64 x 256 threads.
// ---------------------------------------------------------------------------
__global__ __launch_bounds__(256) void k_head(const float* __restrict__ x1,
                                              const float* __restrict__ x2,
                                              const float* __restrict__ cw1,
                                              const float* __restrict__ cb1,
                                              const float* __restrict__ cw2,
                                              const float* __restrict__ cb2,
                                              float* __restrict__ out) {
  __shared__ float xc[256];
  __shared__ float hid[128];
  __shared__ float red[128];
  const int b = blockIdx.x, t = threadIdx.x;
  const float* src = (t < 128) ? x1 : x2;
  const int f = t & 127;
  const size_t base = (size_t)b * NPG;
  float m = -1e30f;
  for (int p = 0; p < NPG; p += 4) {
    const float v0 = src[(base + p + 0) * HDIM + f];
    const float v1 = src[(base + p + 1) * HDIM + f];
    const float v2 = src[(base + p + 2) * HDIM + f];
    const float v3 = src[(base + p + 3) * HDIM + f];
    m = fmaxf(m, fmaxf(fmaxf(v0, v1), fmaxf(v2, v3)));
  }
  xc[t] = m;
  __syncthreads();
  if (t < 128) {
    float acc = cb1[t];
    for (int f2 = 0; f2 < 256; ++f2) acc = fmaf(xc[f2], cw1[f2 * HDIM + t], acc);
    hid[t] = fmaxf(acc, 0.f);
  }
  __syncthreads();
  if (t < 128) red[t] = hid[t] * cw2[t * 2 + 0];
  __syncthreads();
  for (int s = 64; s > 0; s >>= 1) {
    if (t < s) red[t] += red[t + s];
    __syncthreads();
  }
  float l0 = 0.f;
  if (t == 0) l0 = red[0] + cb2[0];
  __syncthreads();
  if (t < 128) red[t] = hid[t] * cw2[t * 2 + 1];
  __syncthreads();
  for (int s = 64; s > 0; s >>= 1) {
    if (t < s) red[t] += red[t + s];
    __syncthreads();
  }
  if (t == 0) {
    const float l1 = red[0] + cb2[1];
    const float mm = fmaxf(l0, l1);
    const float lse = mm + logf(__expf(l0 - mm) + __expf(l1 - mm));
    out[b * 2 + 0] = l0 - lse;
    out[b * 2 + 1] = l1 - lse;
  }
}

// ---------------------------------------------------------------------------
extern "C" void kernel_launch(void* const* d_in, const int* in_sizes, int n_in,
                              void* d_out, int out_size, void* d_ws, size_t ws_size,
                              hipStream_t stream) {
  (void)in_sizes; (void)n_in; (void)out_size; (void)ws_size;
  const float* x      = (const float*)d_in[0];
  // d_in[1] = batch (implicit: n / 1024)
  const float* w0     = (const float*)d_in[2];
  const float* b0     = (const float*)d_in[3];
  const float* c1_mw1 = (const float*)d_in[4];
  const float* c1_mb1 = (const float*)d_in[5];
  const float* c1_mw2 = (const float*)d_in[6];
  const float* c1_mb2 = (const float*)d_in[7];
  const float* c1_gw  = (const float*)d_in[8];
  const float* c1_gb  = (const float*)d_in[9];
  const float* c2_mw1 = (const float*)d_in[10];
  const float* c2_mb1 = (const float*)d_in[11];
  const float* c2_mw2 = (const float*)d_in[12];
  const float* c2_mb2 = (const float*)d_in[13];
  const float* c2_gw  = (const float*)d_in[14];
  const float* c2_gb  = (const float*)d_in[15];
  const float* cw1    = (const float*)d_in[16];
  const float* cb1    = (const float*)d_in[17];
  const float* cw2    = (const float*)d_in[18];
  const float* cb2    = (const float*)d_in[19];

  const size_t NF = (size_t)NTOT * HDIM;   // 8388608 elements
  float* ws  = (float*)d_ws;
  float* xh  = ws;                         // NF fp32 (also reused as x2 output)
  float* x1v = ws + 1 * NF;                // NF fp32
  _Float16* hb = (_Float16*)(ws + 2 * NF);
  _Float16* a1v = hb;                      // NF fp16
  _Float16* a2v = hb + 1 * NF;
  _Float16* uv  = hb + 2 * NF;
  _Float16* vv_ = hb + 3 * NF;
  float* sqv = (float*)(hb + 4 * NF);      // NTOT fp32
  int* nbrv  = (int*)(sqv + NTOT);         // NTOT*8 ints
  float* x2v = xh;                         // alias: xh dead after conv1
  // total ws use: ~137 MB

  k_embed<<<2048, 256, 0, stream>>>(x, w0, b0, xh, sqv);
  k_knn<<<512, 256, 0, stream>>>(xh, sqv, nbrv);

  k_nodegemm<<<dim3(512, 4), 256, 0, stream>>>(xh, c1_mw1, c1_gw, c1_mb1, c1_gb,
                                               a1v, a2v, uv, vv_);
  k_conv<<<4096, 256, 0, stream>>>(xh, nbrv, x, a1v, a2v, uv, vv_,
                                   c1_mw1, c1_mw2, c1_mb2, c1_gw, x1v);

  k_nodegemm<<<dim3(512, 4), 256, 0, stream>>>(x1v, c2_mw1, c2_gw, c2_mb1, c2_gb,
                                               a1v, a2v, uv, vv_);
  k_conv<<<4096, 256, 0, stream>>>(x1v, nbrv, x, a1v, a2v, uv, vv_,
                                   c2_mw1, c2_mw2, c2_mb2, c2_gw, x2v);

  k_head<<<64, 256, 0, stream>>>(x1v, x2v, cw1, cb1, cw2, cb2, (float*)d_out);
}

// Round 5
// 796.027 us; speedup vs baseline: 1.3510x; 1.3510x over previous
//
#include <hip/hip_runtime.h>
#include <math.h>
#include <stdint.h>

// Problem constants
#define NTOT   65536
#define NPG    1024
#define KNN    8
#define HDIM   128
#define XSTR   33     // x row stride (32 feat + 1 kf)
#define NEG    0.2f

typedef _Float16 h2 __attribute__((ext_vector_type(2)));
typedef short bf16x8 __attribute__((ext_vector_type(8)));
typedef float f32x4 __attribute__((ext_vector_type(4)));
typedef unsigned short u16;
typedef unsigned int u32;

#if defined(__has_builtin)
#if __has_builtin(__builtin_amdgcn_fdot2)
#define HAVE_FDOT2 1
#endif
#endif

__device__ __forceinline__ float fdot2f(h2 a, h2 b, float c) {
#ifdef HAVE_FDOT2
  return __builtin_amdgcn_fdot2(a, b, c, false);
#else
  return c + (float)a.x * (float)b.x + (float)a.y * (float)b.y;
#endif
}

__device__ __forceinline__ u16 f2bf(float f) {  // RNE float->bf16
  const u32 u = __builtin_bit_cast(u32, f);
  return (u16)((u + 0x7FFFu + ((u >> 16) & 1u)) >> 16);
}
__device__ __forceinline__ float bf2f(u16 h) {
  return __builtin_bit_cast(float, ((u32)h) << 16);
}
__device__ __forceinline__ void bf8_to_f(const u16* __restrict__ p, float* f) {
  const uint4 v = *reinterpret_cast<const uint4*>(p);
  const u32 w[4] = {v.x, v.y, v.z, v.w};
#pragma unroll
  for (int i = 0; i < 4; ++i) {
    f[2 * i]     = bf2f((u16)(w[i] & 0xffffu));
    f[2 * i + 1] = bf2f((u16)(w[i] >> 16));
  }
}

// ---------------------------------------------------------------------------
// K0: xh = relu(feat @ w0 + b0) -> split bf16 (hi, lo); sq[n] = sum(xh^2) fp32
// ---------------------------------------------------------------------------
__global__ __launch_bounds__(256) void k_embed(const float* __restrict__ x,
                                               const float* __restrict__ w0,
                                               const float* __restrict__ b0,
                                               u16* __restrict__ xh_hi,
                                               u16* __restrict__ xh_lo,
                                               float* __restrict__ sq) {
  __shared__ float w0s[32 * HDIM];
  __shared__ float fs[2][32];
  __shared__ float red[256];
  const int tid = threadIdx.x;
  for (int i = tid; i < 32 * HDIM; i += 256) w0s[i] = w0[i];
  const int h = tid & 127;
  const int nl = tid >> 7;
  const float bias = b0[h];
  for (int it = 0; it < 16; ++it) {
    const int n = blockIdx.x * 32 + it * 2 + nl;
    __syncthreads();
    if (tid < 64) {
      const int r = tid >> 5, f = tid & 31;
      fs[r][f] = x[(size_t)(blockIdx.x * 32 + it * 2 + r) * XSTR + f];
    }
    __syncthreads();
    float acc = bias;
#pragma unroll
    for (int f = 0; f < 32; ++f) acc = fmaf(fs[nl][f], w0s[f * HDIM + h], acc);
    acc = fmaxf(acc, 0.f);
    const u16 hh = f2bf(acc);
    xh_hi[(size_t)n * HDIM + h] = hh;
    xh_lo[(size_t)n * HDIM + h] = f2bf(acc - bf2f(hh));
    red[tid] = acc * acc;
    __syncthreads();
    for (int s = 64; s > 0; s >>= 1) {
      if ((tid & 127) < s) red[tid] += red[tid + s];
      __syncthreads();
    }
    if ((tid & 127) == 0) sq[n] = red[tid];
  }
}

// ---------------------------------------------------------------------------
// K-prep: transpose the 4 node-GEMM weight blocks per layer to bf16 [n][k].
// grid 8 x 256. b = layer*4 + {a1,a2,u,v}
// ---------------------------------------------------------------------------
__global__ __launch_bounds__(256) void k_prep(const float* __restrict__ m1,
                                              const float* __restrict__ g1,
                                              const float* __restrict__ m2,
                                              const float* __restrict__ g2,
                                              u16* __restrict__ Wt) {
  const int b = blockIdx.x;
  const int layer = b >> 2, which = b & 3;
  const float* src = (layer == 0) ? ((which < 2) ? m1 : g1)
                                  : ((which < 2) ? m2 : g2);
  src += (size_t)(which & 1) * 128 * HDIM;
  u16* dst = Wt + (size_t)b * 128 * 128;
  const int t = threadIdx.x;
  const int n = t >> 1, k0 = (t & 1) * 64;
  for (int kk = 0; kk < 64; kk += 2) {
    const float f0 = src[(size_t)(k0 + kk) * HDIM + n];
    const float f1 = src[(size_t)(k0 + kk + 1) * HDIM + n];
    const u32 pk = (u32)f2bf(f0) | ((u32)f2bf(f1) << 16);
    *reinterpret_cast<u32*>(&dst[(size_t)n * 128 + k0 + kk]) = pk;
  }
}

// ---------------------------------------------------------------------------
// K1: per-graph kNN via split-bf16 MFMA (hi*hi + hi*lo + lo*hi, fp32 accum).
// grid 512 (64 graphs x 8 row-blocks of 128), 256 threads = 4 waves.
// Col-tiles of 32; B staged in LDS (XOR-swizzled); Ds[128][33] scan; top-8
// with 2 threads/row, merged (tie -> lowest index).
// ---------------------------------------------------------------------------
__global__ __launch_bounds__(256) void k_knn(const u16* __restrict__ xh_hi,
                                             const u16* __restrict__ xh_lo,
                                             const float* __restrict__ sq,
                                             int* __restrict__ nbr) {
  __shared__ __align__(16) u16 BsH[32 * 128];
  __shared__ __align__(16) u16 BsL[32 * 128];
  __shared__ __align__(16) float Ds[128 * 33];
  __shared__ float sqs[32];
  const int tid = threadIdx.x;
  const int wave = tid >> 6, lane = tid & 63;
  const int fr = lane & 15, fg = lane >> 4;
  const int g = blockIdx.x >> 3;
  const int n0 = (blockIdx.x & 7) * 128;
  const int gbase = g * NPG;

  // A fragments (rows fixed for whole kernel): [2 m-tiles][4 k-tiles]
  bf16x8 aH[2][4], aL[2][4];
#pragma unroll
  for (int mt = 0; mt < 2; ++mt)
#pragma unroll
    for (int kt = 0; kt < 4; ++kt) {
      const size_t off =
          (size_t)(gbase + n0 + wave * 32 + mt * 16 + fr) * HDIM + kt * 32 + fg * 8;
      aH[mt][kt] = *reinterpret_cast<const bf16x8*>(&xh_hi[off]);
      aL[mt][kt] = *reinterpret_cast<const bf16x8*>(&xh_lo[off]);
    }

  const int srow = tid >> 1, shalf = tid & 1;
  const int nglob = gbase + n0 + srow;
  float bd[8];
  int bi[8];
#pragma unroll
  for (int i = 0; i < 8; ++i) { bd[i] = 1e30f; bi[i] = 0; }

  char* BsHc = reinterpret_cast<char*>(BsH);
  char* BsLc = reinterpret_cast<char*>(BsL);

  for (int ct = 0; ct < 32; ++ct) {
    const int m0 = gbase + ct * 32;
    __syncthreads();  // prior scan done (Ds, sqs, Bs reusable)
    if (tid < 32) sqs[tid] = sq[m0 + tid];
    {  // stage B tile: 32 cols x 128 k (hi & lo), XOR-swizzled rows of 256B
      const int col = tid >> 3, kc = (tid & 7) * 16;
      const size_t off = (size_t)(m0 + col) * HDIM + kc;
      const uint4 h0 = *reinterpret_cast<const uint4*>(&xh_hi[off]);
      const uint4 h1 = *reinterpret_cast<const uint4*>(&xh_hi[off + 8]);
      const uint4 l0 = *reinterpret_cast<const uint4*>(&xh_lo[off]);
      const uint4 l1 = *reinterpret_cast<const uint4*>(&xh_lo[off + 8]);
      const int base = col * 256, sw = (col & 7) << 4;
      const int kb = kc * 2;
      *reinterpret_cast<uint4*>(BsHc + base + ((kb) ^ sw)) = h0;
      *reinterpret_cast<uint4*>(BsHc + base + ((kb + 16) ^ sw)) = h1;
      *reinterpret_cast<uint4*>(BsLc + base + ((kb) ^ sw)) = l0;
      *reinterpret_cast<uint4*>(BsLc + base + ((kb + 16) ^ sw)) = l1;
    }
    __syncthreads();
    f32x4 acc[2][2];
#pragma unroll
    for (int mt = 0; mt < 2; ++mt)
#pragma unroll
      for (int nt = 0; nt < 2; ++nt) acc[mt][nt] = (f32x4){0.f, 0.f, 0.f, 0.f};
#pragma unroll
    for (int nt = 0; nt < 2; ++nt) {
      bf16x8 bH[4], bL[4];
      const int col = nt * 16 + fr;
      const int base = col * 256, sw = (col & 7) << 4;
#pragma unroll
      for (int kt = 0; kt < 4; ++kt) {
        const int kb = (kt * 32 + fg * 8) * 2;
        bH[kt] = *reinterpret_cast<const bf16x8*>(BsHc + base + (kb ^ sw));
        bL[kt] = *reinterpret_cast<const bf16x8*>(BsLc + base + (kb ^ sw));
      }
#pragma unroll
      for (int mt = 0; mt < 2; ++mt)
#pragma unroll
        for (int kt = 0; kt < 4; ++kt) {
          acc[mt][nt] = __builtin_amdgcn_mfma_f32_16x16x32_bf16(
              aH[mt][kt], bH[kt], acc[mt][nt], 0, 0, 0);
          acc[mt][nt] = __builtin_amdgcn_mfma_f32_16x16x32_bf16(
              aH[mt][kt], bL[kt], acc[mt][nt], 0, 0, 0);
          acc[mt][nt] = __builtin_amdgcn_mfma_f32_16x16x32_bf16(
              aL[mt][kt], bH[kt], acc[mt][nt], 0, 0, 0);
        }
    }
    // D -> LDS (row = (lane>>4)*4 + reg, col = lane&15)
#pragma unroll
    for (int mt = 0; mt < 2; ++mt)
#pragma unroll
      for (int nt = 0; nt < 2; ++nt)
#pragma unroll
        for (int r = 0; r < 4; ++r)
          Ds[(wave * 32 + mt * 16 + fg * 4 + r) * 33 + nt * 16 + fr] =
              acc[mt][nt][r];
    __syncthreads();
    // scan this tile: thread (srow, shalf) scans 16 columns, m increasing
#pragma unroll
    for (int c2 = 0; c2 < 16; ++c2) {
      const int c = shalf * 16 + c2;
      const int m = m0 + c;
      const float d = sqs[c] - 2.f * Ds[srow * 33 + c];  // sqn dropped (rank-safe)
      if ((m != nglob) && (d < bd[7])) {
        bd[7] = d; bi[7] = m;
#pragma unroll
        for (int q = 7; q > 0; --q) {
          if (bd[q] < bd[q - 1]) {
            const float td = bd[q]; bd[q] = bd[q - 1]; bd[q - 1] = td;
            const int ti = bi[q]; bi[q] = bi[q - 1]; bi[q - 1] = ti;
          }
        }
      }
    }
  }
  __syncthreads();
  // merge the two half-lists per row (tie -> lower index)
  float* mdist = Ds;                          // 2048 floats fit (4224)
  int* midx = reinterpret_cast<int*>(BsH);    // 2048 ints = 8192B fit exactly
#pragma unroll
  for (int i = 0; i < 8; ++i) { mdist[tid * 8 + i] = bd[i]; midx[tid * 8 + i] = bi[i]; }
  __syncthreads();
  if (shalf == 0) {
    const float* dA = &mdist[(srow * 2) * 8];
    const float* dB = &mdist[(srow * 2 + 1) * 8];
    const int* iA = &midx[(srow * 2) * 8];
    const int* iB = &midx[(srow * 2 + 1) * 8];
    int pa = 0, pb = 0;
    int* outp = &nbr[(size_t)nglob * KNN];
#pragma unroll
    for (int i = 0; i < 8; ++i) {
      const float da = dA[pa], db = dB[pb];
      const bool takeA = (da < db) || ((da == db) && (iA[pa] < iB[pb]));
      outp[i] = takeA ? iA[pa] : iB[pb];
      if (takeA) ++pa; else ++pb;
    }
  }
}

// ---------------------------------------------------------------------------
// K2: node GEMMs via bf16 MFMA. out = xin_b @ W (+bias) -> bf16.
// grid (512, 4) x 256; tile 128x128; wave = 32 rows; W pre-transposed bf16.
// ---------------------------------------------------------------------------
__global__ __launch_bounds__(256) void k_ng(const u16* __restrict__ xin_b,
                                            const u16* __restrict__ WtL,
                                            const float* __restrict__ mb1,
                                            const float* __restrict__ gb,
                                            u16* __restrict__ a1,
                                            u16* __restrict__ a2,
                                            u16* __restrict__ uu,
                                            u16* __restrict__ vv) {
  const int tid = threadIdx.x;
  const int wave = tid >> 6, lane = tid & 63;
  const int fr = lane & 15, fg = lane >> 4;
  const int n0 = blockIdx.x * 128;
  const int cb = blockIdx.y;
  const u16* W = WtL + (size_t)cb * 128 * 128;
  const float* bias = (cb == 0) ? mb1 : (cb == 2) ? gb : nullptr;
  u16* outp = (cb == 0) ? a1 : (cb == 1) ? a2 : (cb == 2) ? uu : vv;

  bf16x8 afr[2][4];
#pragma unroll
  for (int mt = 0; mt < 2; ++mt)
#pragma unroll
    for (int kt = 0; kt < 4; ++kt)
      afr[mt][kt] = *reinterpret_cast<const bf16x8*>(
          &xin_b[(size_t)(n0 + wave * 32 + mt * 16 + fr) * HDIM + kt * 32 + fg * 8]);

#pragma unroll
  for (int nt = 0; nt < 8; ++nt) {
    const int col = nt * 16 + fr;
    bf16x8 bfr[4];
#pragma unroll
    for (int kt = 0; kt < 4; ++kt)
      bfr[kt] = *reinterpret_cast<const bf16x8*>(&W[(size_t)col * 128 + kt * 32 + fg * 8]);
    const float bv = bias ? bias[col] : 0.f;
#pragma unroll
    for (int mt = 0; mt < 2; ++mt) {
      f32x4 acc = (f32x4){0.f, 0.f, 0.f, 0.f};
#pragma unroll
      for (int kt = 0; kt < 4; ++kt)
        acc = __builtin_amdgcn_mfma_f32_16x16x32_bf16(afr[mt][kt], bfr[kt], acc, 0, 0, 0);
      const int rbase = n0 + wave * 32 + mt * 16 + fg * 4;
#pragma unroll
      for (int r = 0; r < 4; ++r)
        outp[(size_t)(rbase + r) * HDIM + col] = f2bf(acc[r] + bv);
    }
  }
}

// ---------------------------------------------------------------------------
// K3: fused highway edge conv (bf16 inputs, fdot2 f16 edge GEMM, bf16 out).
// grid 4096 x 256. 16 nodes (128 edges)/block.
// ---------------------------------------------------------------------------
__global__ __launch_bounds__(256) void k_conv(const u16* __restrict__ xin,
                                              const int* __restrict__ nbr,
                                              const float* __restrict__ xraw,
                                              const u16* __restrict__ a1,
                                              const u16* __restrict__ a2,
                                              const u16* __restrict__ uu,
                                              const u16* __restrict__ vv,
                                              const float* __restrict__ mw1,
                                              const float* __restrict__ mw2,
                                              const float* __restrict__ mb2,
                                              const float* __restrict__ gw,
                                              u16* __restrict__ xout) {
  __shared__ __align__(16) h2 Et[64][128];
  __shared__ __align__(16) h2 Ws[64][128];
  __shared__ int jn[128];
  __shared__ float fdv[128];
  __shared__ float w1rs[HDIM];
  __shared__ float gwrs[HDIM];
  const int tid = threadIdx.x;
  const int i0 = blockIdx.x * 16;

  if (tid < 128) {
    w1rs[tid] = mw1[256 * HDIM + tid];
    gwrs[tid] = gw[256 * HDIM + tid];
    const int i = i0 + (tid >> 3);
    const int j = nbr[(size_t)i * KNN + (tid & 7)];
    jn[tid] = j;
    fdv[tid] = xraw[(size_t)i * XSTR + 32] - xraw[(size_t)j * XSTR + 32];
  }
#pragma unroll
  for (int c = 0; c < 8; ++c) {
    const int s = tid + c * 256;
    const int k2 = s >> 5, h4 = s & 31;
    const float4 va = *reinterpret_cast<const float4*>(&mw2[(size_t)(2 * k2) * HDIM + h4 * 4]);
    const float4 vb = *reinterpret_cast<const float4*>(&mw2[(size_t)(2 * k2 + 1) * HDIM + h4 * 4]);
    h2 t0; t0.x = (_Float16)va.x; t0.y = (_Float16)vb.x; Ws[k2][h4 * 4 + 0] = t0;
    h2 t1; t1.x = (_Float16)va.y; t1.y = (_Float16)vb.y; Ws[k2][h4 * 4 + 1] = t1;
    h2 t2; t2.x = (_Float16)va.z; t2.y = (_Float16)vb.z; Ws[k2][h4 * 4 + 2] = t2;
    h2 t3; t3.x = (_Float16)va.w; t3.y = (_Float16)vb.w; Ws[k2][h4 * 4 + 3] = t3;
  }
  __syncthreads();
  {
    const int e = tid >> 1;
    const int kk0 = (tid & 1) * 64;
    const int inode = i0 + (e >> 3);
    const int j = jn[e];
    const float fd = fdv[e];
#pragma unroll
    for (int s8 = 0; s8 < 8; ++s8) {
      const int kk = kk0 + s8 * 8;
      float fa[8], fb[8];
      bf8_to_f(&a1[(size_t)inode * HDIM + kk], fa);
      bf8_to_f(&a2[(size_t)j * HDIM + kk], fb);
      float p[8];
#pragma unroll
      for (int q = 0; q < 8; ++q)
        p[q] = fmaxf(fa[q] + fb[q] + fd * w1rs[kk + q], 0.f);
      h2 e0; e0.x = (_Float16)p[0]; e0.y = (_Float16)p[1];
      h2 e1; e1.x = (_Float16)p[2]; e1.y = (_Float16)p[3];
      h2 e2; e2.x = (_Float16)p[4]; e2.y = (_Float16)p[5];
      h2 e3; e3.x = (_Float16)p[6]; e3.y = (_Float16)p[7];
      Et[(kk >> 1) + 0][e] = e0;
      Et[(kk >> 1) + 1][e] = e1;
      Et[(kk >> 1) + 2][e] = e2;
      Et[(kk >> 1) + 3][e] = e3;
    }
  }
  __syncthreads();
  const int ty = tid >> 4, tx = tid & 15;
  float acc[8][8];
#pragma unroll
  for (int r = 0; r < 8; ++r)
#pragma unroll
    for (int c = 0; c < 8; ++c) acc[r][c] = 0.f;
  for (int k2 = 0; k2 < 64; ++k2) {
    const uint4 uA0 = *reinterpret_cast<const uint4*>(&Et[k2][ty * 8]);
    const uint4 uA1 = *reinterpret_cast<const uint4*>(&Et[k2][ty * 8 + 4]);
    const uint4 uB0 = *reinterpret_cast<const uint4*>(&Ws[k2][tx * 8]);
    const uint4 uB1 = *reinterpret_cast<const uint4*>(&Ws[k2][tx * 8 + 4]);
    const h2 a[8] = {__builtin_bit_cast(h2, uA0.x), __builtin_bit_cast(h2, uA0.y),
                     __builtin_bit_cast(h2, uA0.z), __builtin_bit_cast(h2, uA0.w),
                     __builtin_bit_cast(h2, uA1.x), __builtin_bit_cast(h2, uA1.y),
                     __builtin_bit_cast(h2, uA1.z), __builtin_bit_cast(h2, uA1.w)};
    const h2 b[8] = {__builtin_bit_cast(h2, uB0.x), __builtin_bit_cast(h2, uB0.y),
                     __builtin_bit_cast(h2, uB0.z), __builtin_bit_cast(h2, uB0.w),
                     __builtin_bit_cast(h2, uB1.x), __builtin_bit_cast(h2, uB1.y),
                     __builtin_bit_cast(h2, uB1.z), __builtin_bit_cast(h2, uB1.w)};
#pragma unroll
    for (int r = 0; r < 8; ++r)
#pragma unroll
      for (int c = 0; c < 8; ++c) acc[r][c] = fdot2f(a[r], b[c], acc[r][c]);
  }
  // epilogue
  const int node = i0 + ty;
  float xi_[8], ui_[8], mb2v[8], gwv[8];
  {
    bf8_to_f(&xin[(size_t)node * HDIM + tx * 8], xi_);
    bf8_to_f(&uu[(size_t)node * HDIM + tx * 8], ui_);
    const float4 m0 = *reinterpret_cast<const float4*>(&mb2[tx * 8]);
    const float4 m1 = *reinterpret_cast<const float4*>(&mb2[tx * 8 + 4]);
    mb2v[0] = m0.x; mb2v[1] = m0.y; mb2v[2] = m0.z; mb2v[3] = m0.w;
    mb2v[4] = m1.x; mb2v[5] = m1.y; mb2v[6] = m1.z; mb2v[7] = m1.w;
#pragma unroll
    for (int c = 0; c < 8; ++c) gwv[c] = gwrs[tx * 8 + c];
  }
  float msum[8];
#pragma unroll
  for (int c = 0; c < 8; ++c) msum[c] = 0.f;
#pragma unroll
  for (int r = 0; r < 8; ++r) {
    const int e = ty * 8 + r;
    const int j = jn[e];
    const float fd = fdv[e];
    float vj[8], xj[8];
    bf8_to_f(&vv[(size_t)j * HDIM + tx * 8], vj);
    bf8_to_f(&xin[(size_t)j * HDIM + tx * 8], xj);
#pragma unroll
    for (int c = 0; c < 8; ++c) {
      const float z = ui_[c] + vj[c] + fd * gwv[c];
      const float gsig = 1.f / (1.f + __expf(-z));
      const float M = acc[r][c] + mb2v[c];
      msum[c] += gsig * M + (1.f - gsig) * xj[c];
    }
  }
  u32 w[4];
#pragma unroll
  for (int i = 0; i < 4; ++i) {
    float t0 = msum[2 * i] * 0.125f + xi_[2 * i];
    float t1 = msum[2 * i + 1] * 0.125f + xi_[2 * i + 1];
    t0 = (t0 > 0.f) ? t0 : NEG * t0;
    t1 = (t1 > 0.f) ? t1 : NEG * t1;
    w[i] = (u32)f2bf(t0) | ((u32)f2bf(t1) << 16);
  }
  *reinterpret_cast<uint4*>(&xout[(size_t)node * HDIM + tx * 8]) =
      make_uint4(w[0], w[1], w[2], w[3]);
}

// ---------------------------------------------------------------------------
// K4: per-graph max-pool over [x1|x2] (bf16), 2-layer head, log_softmax.
// ---------------------------------------------------------------------------
__global__ __launch_bounds__(256) void k_head(const u16* __restrict__ x1,
                                              const u16* __restrict__ x2,
                                              const float* __restrict__ cw1,
                                              const float* __restrict__ cb1,
                                              const float* __restrict__ cw2,
                                              const float* __restrict__ cb2,
                                              float* __restrict__ out) {
  __shared__ float xc[256];
  __shared__ float hid[128];
  __shared__ float red[128];
  const int b = blockIdx.x, t = threadIdx.x;
  const u16* src = (t < 128) ? x1 : x2;
  const int f = t & 127;
  const size_t base = (size_t)b * NPG;
  float m = -1e30f;
  for (int p = 0; p < NPG; p += 4) {
    const float v0 = bf2f(src[(base + p + 0) * HDIM + f]);
    const float v1 = bf2f(src[(base + p + 1) * HDIM + f]);
    const float v2 = bf2f(src[(base + p + 2) * HDIM + f]);
    const float v3 = bf2f(src[(base + p + 3) * HDIM + f]);
    m = fmaxf(m, fmaxf(fmaxf(v0, v1), fmaxf(v2, v3)));
  }
  xc[t] = m;
  __syncthreads();
  if (t < 128) {
    float acc = cb1[t];
    for (int f2 = 0; f2 < 256; ++f2) acc = fmaf(xc[f2], cw1[f2 * HDIM + t], acc);
    hid[t] = fmaxf(acc, 0.f);
  }
  __syncthreads();
  if (t < 128) red[t] = hid[t] * cw2[t * 2 + 0];
  __syncthreads();
  for (int s = 64; s > 0; s >>= 1) {
    if (t < s) red[t] += red[t + s];
    __syncthreads();
  }
  float l0 = 0.f;
  if (t == 0) l0 = red[0] + cb2[0];
  __syncthreads();
  if (t < 128) red[t] = hid[t] * cw2[t * 2 + 1];
  __syncthreads();
  for (int s = 64; s > 0; s >>= 1) {
    if (t < s) red[t] += red[t + s];
    __syncthreads();
  }
  if (t == 0) {
    const float l1 = red[0] + cb2[1];
    const float mm = fmaxf(l0, l1);
    const float lse = mm + logf(__expf(l0 - mm) + __expf(l1 - mm));
    out[b * 2 + 0] = l0 - lse;
    out[b * 2 + 1] = l1 - lse;
  }
}

// ---------------------------------------------------------------------------
extern "C" void kernel_launch(void* const* d_in, const int* in_sizes, int n_in,
                              void* d_out, int out_size, void* d_ws, size_t ws_size,
                              hipStream_t stream) {
  (void)in_sizes; (void)n_in; (void)out_size; (void)ws_size;
  const float* x      = (const float*)d_in[0];
  const float* w0     = (const float*)d_in[2];
  const float* b0     = (const float*)d_in[3];
  const float* c1_mw1 = (const float*)d_in[4];
  const float* c1_mb1 = (const float*)d_in[5];
  const float* c1_mw2 = (const float*)d_in[6];
  const float* c1_mb2 = (const float*)d_in[7];
  const float* c1_gw  = (const float*)d_in[8];
  const float* c1_gb  = (const float*)d_in[9];
  const float* c2_mw1 = (const float*)d_in[10];
  const float* c2_mb1 = (const float*)d_in[11];
  const float* c2_mw2 = (const float*)d_in[12];
  const float* c2_mb2 = (const float*)d_in[13];
  const float* c2_gw  = (const float*)d_in[14];
  const float* c2_gb  = (const float*)d_in[15];
  const float* cw1    = (const float*)d_in[16];
  const float* cb1    = (const float*)d_in[17];
  const float* cw2    = (const float*)d_in[18];
  const float* cb2    = (const float*)d_in[19];

  const size_t NF = (size_t)NTOT * HDIM;  // 8388608 elements
  u16* wsh   = (u16*)d_ws;
  u16* xh_hi = wsh + 0 * NF;
  u16* xh_lo = wsh + 1 * NF;
  u16* x1b   = wsh + 2 * NF;
  u16* x2b   = wsh + 3 * NF;
  u16* a1v   = wsh + 4 * NF;
  u16* a2v   = wsh + 5 * NF;
  u16* uv    = wsh + 6 * NF;
  u16* vv_   = wsh + 7 * NF;
  u16* Wt    = wsh + 8 * NF;                      // 8 * 128*128 bf16
  float* sqv = (float*)(Wt + 8 * 128 * 128);      // NTOT fp32
  int* nbrv  = (int*)(sqv + NTOT);                // NTOT*8 int
  // total ~137 MB (same as the proven round-3 footprint)

  k_prep<<<8, 256, 0, stream>>>(c1_mw1, c1_gw, c2_mw1, c2_gw, Wt);
  k_embed<<<2048, 256, 0, stream>>>(x, w0, b0, xh_hi, xh_lo, sqv);
  k_knn<<<512, 256, 0, stream>>>(xh_hi, xh_lo, sqv, nbrv);

  k_ng<<<dim3(512, 4), 256, 0, stream>>>(xh_hi, Wt, c1_mb1, c1_gb,
                                         a1v, a2v, uv, vv_);
  k_conv<<<4096, 256, 0, stream>>>(xh_hi, nbrv, x, a1v, a2v, uv, vv_,
                                   c1_mw1, c1_mw2, c1_mb2, c1_gw, x1b);

  k_ng<<<dim3(512, 4), 256, 0, stream>>>(x1b, Wt + 4 * 128 * 128, c2_mb1, c2_gb,
                                         a1v, a2v, uv, vv_);
  k_conv<<<4096, 256, 0, stream>>>(x1b, nbrv, x, a1v, a2v, uv, vv_,
                                   c2_mw1, c2_mw2, c2_mb2, c2_gw, x2b);

  k_head<<<64, 256, 0, stream>>>(x1b, x2b, cw1, cb1, cw2, cb2, (float*)d_out);
}

// Round 8
// 724.813 us; speedup vs baseline: 1.4838x; 1.0983x over previous
//
#include <hip/hip_runtime.h>
#include <math.h>
#include <stdint.h>

// Problem constants
#define NTOT   65536
#define NPG    1024
#define KNN    8
#define HDIM   128
#define XSTR   33     // x row stride (32 feat + 1 kf)
#define NEG    0.2f

typedef _Float16 h2 __attribute__((ext_vector_type(2)));
typedef _Float16 h8 __attribute__((ext_vector_type(8)));   // f16x8 MFMA frag
typedef short bf16x8 __attribute__((ext_vector_type(8)));
typedef float f32x4 __attribute__((ext_vector_type(4)));
typedef unsigned short u16;
typedef unsigned int u32;

__device__ __forceinline__ u16 f2bf(float f) {  // RNE float->bf16
  const u32 u = __builtin_bit_cast(u32, f);
  return (u16)((u + 0x7FFFu + ((u >> 16) & 1u)) >> 16);
}
__device__ __forceinline__ float bf2f(u16 h) {
  return __builtin_bit_cast(float, ((u32)h) << 16);
}
__device__ __forceinline__ void bf8_to_f(const u16* __restrict__ p, float* f) {
  const uint4 v = *reinterpret_cast<const uint4*>(p);
  const u32 w[4] = {v.x, v.y, v.z, v.w};
#pragma unroll
  for (int i = 0; i < 4; ++i) {
    f[2 * i]     = bf2f((u16)(w[i] & 0xffffu));
    f[2 * i + 1] = bf2f((u16)(w[i] >> 16));
  }
}

// ---------------------------------------------------------------------------
// K0: xh = relu(feat @ w0 + b0) -> split bf16 (hi, lo); sq[n] = sum(xh^2) fp32
// ---------------------------------------------------------------------------
__global__ __launch_bounds__(256) void k_embed(const float* __restrict__ x,
                                               const float* __restrict__ w0,
                                               const float* __restrict__ b0,
                                               u16* __restrict__ xh_hi,
                                               u16* __restrict__ xh_lo,
                                               float* __restrict__ sq) {
  __shared__ float w0s[32 * HDIM];
  __shared__ float fs[2][32];
  __shared__ float red[256];
  const int tid = threadIdx.x;
  for (int i = tid; i < 32 * HDIM; i += 256) w0s[i] = w0[i];
  const int h = tid & 127;
  const int nl = tid >> 7;
  const float bias = b0[h];
  for (int it = 0; it < 16; ++it) {
    const int n = blockIdx.x * 32 + it * 2 + nl;
    __syncthreads();
    if (tid < 64) {
      const int r = tid >> 5, f = tid & 31;
      fs[r][f] = x[(size_t)(blockIdx.x * 32 + it * 2 + r) * XSTR + f];
    }
    __syncthreads();
    float acc = bias;
#pragma unroll
    for (int f = 0; f < 32; ++f) acc = fmaf(fs[nl][f], w0s[f * HDIM + h], acc);
    acc = fmaxf(acc, 0.f);
    const u16 hh = f2bf(acc);
    xh_hi[(size_t)n * HDIM + h] = hh;
    xh_lo[(size_t)n * HDIM + h] = f2bf(acc - bf2f(hh));
    red[tid] = acc * acc;
    __syncthreads();
    for (int s = 64; s > 0; s >>= 1) {
      if ((tid & 127) < s) red[tid] += red[tid + s];
      __syncthreads();
    }
    if ((tid & 127) == 0) sq[n] = red[tid];
  }
}

// ---------------------------------------------------------------------------
// K-prep: b 0..7: transpose node-GEMM weight blocks to bf16 [n][k].
//          b 8..9: transpose mw2 (layer 1/2) to f16 [h][k].
// grid 10 x 256.
// ---------------------------------------------------------------------------
__global__ __launch_bounds__(256) void k_prep(const float* __restrict__ m1,
                                              const float* __restrict__ g1,
                                              const float* __restrict__ m2,
                                              const float* __restrict__ g2,
                                              const float* __restrict__ w2a,
                                              const float* __restrict__ w2b,
                                              u16* __restrict__ Wt) {
  const int b = blockIdx.x;
  const int t = threadIdx.x;
  const int n = t >> 1, k0 = (t & 1) * 64;
  u16* dst = Wt + (size_t)b * 128 * 128;
  if (b < 8) {
    const int layer = b >> 2, which = b & 3;
    const float* src = (layer == 0) ? ((which < 2) ? m1 : g1)
                                    : ((which < 2) ? m2 : g2);
    src += (size_t)(which & 1) * 128 * HDIM;
    for (int kk = 0; kk < 64; kk += 2) {
      const float f0 = src[(size_t)(k0 + kk) * HDIM + n];
      const float f1 = src[(size_t)(k0 + kk + 1) * HDIM + n];
      const u32 pk = (u32)f2bf(f0) | ((u32)f2bf(f1) << 16);
      *reinterpret_cast<u32*>(&dst[(size_t)n * 128 + k0 + kk]) = pk;
    }
  } else {
    const float* src = (b == 8) ? w2a : w2b;
    for (int kk = 0; kk < 64; kk += 2) {
      const float f0 = src[(size_t)(k0 + kk) * HDIM + n];
      const float f1 = src[(size_t)(k0 + kk + 1) * HDIM + n];
      const u16 h0 = __builtin_bit_cast(u16, (_Float16)f0);
      const u16 h1 = __builtin_bit_cast(u16, (_Float16)f1);
      const u32 pk = (u32)h0 | ((u32)h1 << 16);
      *reinterpret_cast<u32*>(&dst[(size_t)n * 128 + k0 + kk]) = pk;
    }
  }
}

// ---------------------------------------------------------------------------
// K1: per-graph kNN via split-bf16 MFMA (hi*hi + hi*lo + lo*hi, fp32 accum).
// grid 512 (64 graphs x 8 row-blocks of 128), 256 threads = 4 waves.
// ---------------------------------------------------------------------------
__global__ __launch_bounds__(256) void k_knn(const u16* __restrict__ xh_hi,
                                             const u16* __restrict__ xh_lo,
                                             const float* __restrict__ sq,
                                             int* __restrict__ nbr) {
  __shared__ __align__(16) u16 BsH[32 * 128];
  __shared__ __align__(16) u16 BsL[32 * 128];
  __shared__ __align__(16) float Ds[128 * 33];
  __shared__ float sqs[32];
  const int tid = threadIdx.x;
  const int wave = tid >> 6, lane = tid & 63;
  const int fr = lane & 15, fg = lane >> 4;
  const int g = blockIdx.x >> 3;
  const int n0 = (blockIdx.x & 7) * 128;
  const int gbase = g * NPG;

  bf16x8 aH[2][4], aL[2][4];
#pragma unroll
  for (int mt = 0; mt < 2; ++mt)
#pragma unroll
    for (int kt = 0; kt < 4; ++kt) {
      const size_t off =
          (size_t)(gbase + n0 + wave * 32 + mt * 16 + fr) * HDIM + kt * 32 + fg * 8;
      aH[mt][kt] = *reinterpret_cast<const bf16x8*>(&xh_hi[off]);
      aL[mt][kt] = *reinterpret_cast<const bf16x8*>(&xh_lo[off]);
    }

  const int srow = tid >> 1, shalf = tid & 1;
  const int nglob = gbase + n0 + srow;
  float bd[8];
  int bi[8];
#pragma unroll
  for (int i = 0; i < 8; ++i) { bd[i] = 1e30f; bi[i] = 0; }

  char* BsHc = reinterpret_cast<char*>(BsH);
  char* BsLc = reinterpret_cast<char*>(BsL);

  for (int ct = 0; ct < 32; ++ct) {
    const int m0 = gbase + ct * 32;
    __syncthreads();
    if (tid < 32) sqs[tid] = sq[m0 + tid];
    {
      const int col = tid >> 3, kc = (tid & 7) * 16;
      const size_t off = (size_t)(m0 + col) * HDIM + kc;
      const uint4 h0 = *reinterpret_cast<const uint4*>(&xh_hi[off]);
      const uint4 h1 = *reinterpret_cast<const uint4*>(&xh_hi[off + 8]);
      const uint4 l0 = *reinterpret_cast<const uint4*>(&xh_lo[off]);
      const uint4 l1 = *reinterpret_cast<const uint4*>(&xh_lo[off + 8]);
      const int base = col * 256, sw = (col & 7) << 4;
      const int kb = kc * 2;
      *reinterpret_cast<uint4*>(BsHc + base + ((kb) ^ sw)) = h0;
      *reinterpret_cast<uint4*>(BsHc + base + ((kb + 16) ^ sw)) = h1;
      *reinterpret_cast<uint4*>(BsLc + base + ((kb) ^ sw)) = l0;
      *reinterpret_cast<uint4*>(BsLc + base + ((kb + 16) ^ sw)) = l1;
    }
    __syncthreads();
    f32x4 acc[2][2];
#pragma unroll
    for (int mt = 0; mt < 2; ++mt)
#pragma unroll
      for (int nt = 0; nt < 2; ++nt) acc[mt][nt] = (f32x4){0.f, 0.f, 0.f, 0.f};
#pragma unroll
    for (int nt = 0; nt < 2; ++nt) {
      bf16x8 bH[4], bL[4];
      const int col = nt * 16 + fr;
      const int base = col * 256, sw = (col & 7) << 4;
#pragma unroll
      for (int kt = 0; kt < 4; ++kt) {
        const int kb = (kt * 32 + fg * 8) * 2;
        bH[kt] = *reinterpret_cast<const bf16x8*>(BsHc + base + (kb ^ sw));
        bL[kt] = *reinterpret_cast<const bf16x8*>(BsLc + base + (kb ^ sw));
      }
#pragma unroll
      for (int mt = 0; mt < 2; ++mt)
#pragma unroll
        for (int kt = 0; kt < 4; ++kt) {
          acc[mt][nt] = __builtin_amdgcn_mfma_f32_16x16x32_bf16(
              aH[mt][kt], bH[kt], acc[mt][nt], 0, 0, 0);
          acc[mt][nt] = __builtin_amdgcn_mfma_f32_16x16x32_bf16(
              aH[mt][kt], bL[kt], acc[mt][nt], 0, 0, 0);
          acc[mt][nt] = __builtin_amdgcn_mfma_f32_16x16x32_bf16(
              aL[mt][kt], bH[kt], acc[mt][nt], 0, 0, 0);
        }
    }
#pragma unroll
    for (int mt = 0; mt < 2; ++mt)
#pragma unroll
      for (int nt = 0; nt < 2; ++nt)
#pragma unroll
        for (int r = 0; r < 4; ++r)
          Ds[(wave * 32 + mt * 16 + fg * 4 + r) * 33 + nt * 16 + fr] =
              acc[mt][nt][r];
    __syncthreads();
#pragma unroll
    for (int c2 = 0; c2 < 16; ++c2) {
      const int c = shalf * 16 + c2;
      const int m = m0 + c;
      const float d = sqs[c] - 2.f * Ds[srow * 33 + c];
      if ((m != nglob) && (d < bd[7])) {
        bd[7] = d; bi[7] = m;
#pragma unroll
        for (int q = 7; q > 0; --q) {
          if (bd[q] < bd[q - 1]) {
            const float td = bd[q]; bd[q] = bd[q - 1]; bd[q - 1] = td;
            const int ti = bi[q]; bi[q] = bi[q - 1]; bi[q - 1] = ti;
          }
        }
      }
    }
  }
  __syncthreads();
  float* mdist = Ds;
  int* midx = reinterpret_cast<int*>(BsH);
#pragma unroll
  for (int i = 0; i < 8; ++i) { mdist[tid * 8 + i] = bd[i]; midx[tid * 8 + i] = bi[i]; }
  __syncthreads();
  if (shalf == 0) {
    const float* dA = &mdist[(srow * 2) * 8];
    const float* dB = &mdist[(srow * 2 + 1) * 8];
    const int* iA = &midx[(srow * 2) * 8];
    const int* iB = &midx[(srow * 2 + 1) * 8];
    int pa = 0, pb = 0;
    int* outp = &nbr[(size_t)nglob * KNN];
#pragma unroll
    for (int i = 0; i < 8; ++i) {
      const float da = dA[pa], db = dB[pb];
      const bool takeA = (da < db) || ((da == db) && (iA[pa] < iB[pb]));
      outp[i] = takeA ? iA[pa] : iB[pb];
      if (takeA) ++pa; else ++pb;
    }
  }
}

// ---------------------------------------------------------------------------
// K2: node GEMMs via bf16 MFMA. out = xin_b @ W (+bias) -> bf16.
// ---------------------------------------------------------------------------
__global__ __launch_bounds__(256) void k_ng(const u16* __restrict__ xin_b,
                                            const u16* __restrict__ WtL,
                                            const float* __restrict__ mb1,
                                            const float* __restrict__ gb,
                                            u16* __restrict__ a1,
                                            u16* __restrict__ a2,
                                            u16* __restrict__ uu,
                                            u16* __restrict__ vv) {
  const int tid = threadIdx.x;
  const int wave = tid >> 6, lane = tid & 63;
  const int fr = lane & 15, fg = lane >> 4;
  const int n0 = blockIdx.x * 128;
  const int cb = blockIdx.y;
  const u16* W = WtL + (size_t)cb * 128 * 128;
  const float* bias = (cb == 0) ? mb1 : (cb == 2) ? gb : nullptr;
  u16* outp = (cb == 0) ? a1 : (cb == 1) ? a2 : (cb == 2) ? uu : vv;

  bf16x8 afr[2][4];
#pragma unroll
  for (int mt = 0; mt < 2; ++mt)
#pragma unroll
    for (int kt = 0; kt < 4; ++kt)
      afr[mt][kt] = *reinterpret_cast<const bf16x8*>(
          &xin_b[(size_t)(n0 + wave * 32 + mt * 16 + fr) * HDIM + kt * 32 + fg * 8]);

#pragma unroll
  for (int nt = 0; nt < 8; ++nt) {
    const int col = nt * 16 + fr;
    bf16x8 bfr[4];
#pragma unroll
    for (int kt = 0; kt < 4; ++kt)
      bfr[kt] = *reinterpret_cast<const bf16x8*>(&W[(size_t)col * 128 + kt * 32 + fg * 8]);
    const float bv = bias ? bias[col] : 0.f;
#pragma unroll
    for (int mt = 0; mt < 2; ++mt) {
      f32x4 acc = (f32x4){0.f, 0.f, 0.f, 0.f};
#pragma unroll
      for (int kt = 0; kt < 4; ++kt)
        acc = __builtin_amdgcn_mfma_f32_16x16x32_bf16(afr[mt][kt], bfr[kt], acc, 0, 0, 0);
      const int rbase = n0 + wave * 32 + mt * 16 + fg * 4;
#pragma unroll
      for (int r = 0; r < 4; ++r)
        outp[(size_t)(rbase + r) * HDIM + col] = f2bf(acc[r] + bv);
    }
  }
}

// ---------------------------------------------------------------------------
// K3: fused highway edge conv, MFMA edition.
// E (128 edges x 128 k, f16) built directly in A-fragment registers;
// M = E @ mw2t^T via mfma_f32_16x16x32_f16; M staged f32 in LDS; epilogue
// (gate/mean/skip/leaky) identical to the verified round-5 path.
// grid 4096 x 256 (4 waves).
// ---------------------------------------------------------------------------
__global__ __launch_bounds__(256) void k_conv(const u16* __restrict__ xin,
                                              const int* __restrict__ nbr,
                                              const float* __restrict__ xraw,
                                              const u16* __restrict__ a1,
                                              const u16* __restrict__ a2,
                                              const u16* __restrict__ uu,
                                              const u16* __restrict__ vv,
                                              const float* __restrict__ mw1,
                                              const u16* __restrict__ mw2t,  // f16 [h][k]
                                              const float* __restrict__ mb2,
                                              const float* __restrict__ gw,
                                              u16* __restrict__ xout) {
  __shared__ __align__(16) float Ms[128 * 132];  // 67584 B
  __shared__ int jn[128];
  __shared__ float fdv[128];
  __shared__ float w1rs[HDIM];
  __shared__ float gwrs[HDIM];
  const int tid = threadIdx.x;
  const int i0 = blockIdx.x * 16;

  if (tid < 128) {
    w1rs[tid] = mw1[256 * HDIM + tid];
    gwrs[tid] = gw[256 * HDIM + tid];
    const int i = i0 + (tid >> 3);
    const int j = nbr[(size_t)i * KNN + (tid & 7)];
    jn[tid] = j;
    fdv[tid] = xraw[(size_t)i * XSTR + 32] - xraw[(size_t)j * XSTR + 32];
  }
  __syncthreads();

  const int wave = tid >> 6, lane = tid & 63;
  const int fr = lane & 15, fg = lane >> 4;

  // Build E fragments: A-operand rows e = wave*32 + mt*16 + fr, k-slice fg*8.
  h8 efrag[2][4];
#pragma unroll
  for (int mt = 0; mt < 2; ++mt) {
    const int e = wave * 32 + mt * 16 + fr;
    const int inode = i0 + (e >> 3);
    const int j = jn[e];
    const float fd = fdv[e];
#pragma unroll
    for (int kt = 0; kt < 4; ++kt) {
      const int k0 = kt * 32 + fg * 8;
      float fa[8], fb[8];
      bf8_to_f(&a1[(size_t)inode * HDIM + k0], fa);
      bf8_to_f(&a2[(size_t)j * HDIM + k0], fb);
      h8 ef;
#pragma unroll
      for (int q = 0; q < 8; ++q)
        ef[q] = (_Float16)fmaxf(fa[q] + fb[q] + fd * w1rs[k0 + q], 0.f);
      efrag[mt][kt] = ef;
    }
  }

  // M = E @ mw2 (f16 MFMA, fp32 accum); acc[mt][nt]
  f32x4 acc[2][8];
#pragma unroll
  for (int mt = 0; mt < 2; ++mt)
#pragma unroll
    for (int nt = 0; nt < 8; ++nt) acc[mt][nt] = (f32x4){0.f, 0.f, 0.f, 0.f};
#pragma unroll
  for (int nt = 0; nt < 8; ++nt) {
    const int col = nt * 16 + fr;
    h8 bfr[4];
#pragma unroll
    for (int kt = 0; kt < 4; ++kt)
      bfr[kt] = *reinterpret_cast<const h8*>(&mw2t[(size_t)col * 128 + kt * 32 + fg * 8]);
#pragma unroll
    for (int mt = 0; mt < 2; ++mt)
#pragma unroll
      for (int kt = 0; kt < 4; ++kt)
        acc[mt][nt] = __builtin_amdgcn_mfma_f32_16x16x32_f16(
            efrag[mt][kt], bfr[kt], acc[mt][nt], 0, 0, 0);
  }
  // stage M: row = wave*32 + mt*16 + fg*4 + r, col = nt*16 + fr
#pragma unroll
  for (int mt = 0; mt < 2; ++mt)
#pragma unroll
    for (int nt = 0; nt < 8; ++nt)
#pragma unroll
      for (int r = 0; r < 4; ++r)
        Ms[(wave * 32 + mt * 16 + fg * 4 + r) * 132 + nt * 16 + fr] = acc[mt][nt][r];
  __syncthreads();

  // epilogue (round-5 verified layout): ty = node-in-block, tx = col-oct
  const int ty = tid >> 4, tx = tid & 15;
  const int node = i0 + ty;
  float xi_[8], ui_[8], mb2v[8], gwv[8];
  {
    bf8_to_f(&xin[(size_t)node * HDIM + tx * 8], xi_);
    bf8_to_f(&uu[(size_t)node * HDIM + tx * 8], ui_);
    const float4 m0 = *reinterpret_cast<const float4*>(&mb2[tx * 8]);
    const float4 m1 = *reinterpret_cast<const float4*>(&mb2[tx * 8 + 4]);
    mb2v[0] = m0.x; mb2v[1] = m0.y; mb2v[2] = m0.z; mb2v[3] = m0.w;
    mb2v[4] = m1.x; mb2v[5] = m1.y; mb2v[6] = m1.z; mb2v[7] = m1.w;
#pragma unroll
    for (int c = 0; c < 8; ++c) gwv[c] = gwrs[tx * 8 + c];
  }
  float msum[8];
#pragma unroll
  for (int c = 0; c < 8; ++c) msum[c] = 0.f;
#pragma unroll
  for (int r = 0; r < 8; ++r) {
    const int e = ty * 8 + r;
    const int j = jn[e];
    const float fd = fdv[e];
    float vj[8], xj[8];
    bf8_to_f(&vv[(size_t)j * HDIM + tx * 8], vj);
    bf8_to_f(&xin[(size_t)j * HDIM + tx * 8], xj);
    const float4 M0 = *reinterpret_cast<const float4*>(&Ms[e * 132 + tx * 8]);
    const float4 M1 = *reinterpret_cast<const float4*>(&Ms[e * 132 + tx * 8 + 4]);
    const float Mv[8] = {M0.x, M0.y, M0.z, M0.w, M1.x, M1.y, M1.z, M1.w};
#pragma unroll
    for (int c = 0; c < 8; ++c) {
      const float z = ui_[c] + vj[c] + fd * gwv[c];
      const float gsig = 1.f / (1.f + __expf(-z));
      const float M = Mv[c] + mb2v[c];
      msum[c] += gsig * M + (1.f - gsig) * xj[c];
    }
  }
  u32 w[4];
#pragma unroll
  for (int i = 0; i < 4; ++i) {
    float t0 = msum[2 * i] * 0.125f + xi_[2 * i];
    float t1 = msum[2 * i + 1] * 0.125f + xi_[2 * i + 1];
    t0 = (t0 > 0.f) ? t0 : NEG * t0;
    t1 = (t1 > 0.f) ? t1 : NEG * t1;
    w[i] = (u32)f2bf(t0) | ((u32)f2bf(t1) << 16);
  }
  *reinterpret_cast<uint4*>(&xout[(size_t)node * HDIM + tx * 8]) =
      make_uint4(w[0], w[1], w[2], w[3]);
}

// ---------------------------------------------------------------------------
// K4: per-graph max-pool over [x1|x2] (bf16), 2-layer head, log_softmax.
// ---------------------------------------------------------------------------
__global__ __launch_bounds__(256) void k_head(const u16* __restrict__ x1,
                                              const u16* __restrict__ x2,
                                              const float* __restrict__ cw1,
                                              const float* __restrict__ cb1,
                                              const float* __restrict__ cw2,
                                              const float* __restrict__ cb2,
                                              float* __restrict__ out) {
  __shared__ float xc[256];
  __shared__ float hid[128];
  __shared__ float red[128];
  const int b = blockIdx.x, t = threadIdx.x;
  const u16* src = (t < 128) ? x1 : x2;
  const int f = t & 127;
  const size_t base = (size_t)b * NPG;
  float m = -1e30f;
  for (int p = 0; p < NPG; p += 4) {
    const float v0 = bf2f(src[(base + p + 0) * HDIM + f]);
    const float v1 = bf2f(src[(base + p + 1) * HDIM + f]);
    const float v2 = bf2f(src[(base + p + 2) * HDIM + f]);
    const float v3 = bf2f(src[(base + p + 3) * HDIM + f]);
    m = fmaxf(m, fmaxf(fmaxf(v0, v1), fmaxf(v2, v3)));
  }
  xc[t] = m;
  __syncthreads();
  if (t < 128) {
    float acc = cb1[t];
    for (int f2 = 0; f2 < 256; ++f2) acc = fmaf(xc[f2], cw1[f2 * HDIM + t], acc);
    hid[t] = fmaxf(acc, 0.f);
  }
  __syncthreads();
  if (t < 128) red[t] = hid[t] * cw2[t * 2 + 0];
  __syncthreads();
  for (int s = 64; s > 0; s >>= 1) {
    if (t < s) red[t] += red[t + s];
    __syncthreads();
  }
  float l0 = 0.f;
  if (t == 0) l0 = red[0] + cb2[0];
  __syncthreads();
  if (t < 128) red[t] = hid[t] * cw2[t * 2 + 1];
  __syncthreads();
  for (int s = 64; s > 0; s >>= 1) {
    if (t < s) red[t] += red[t + s];
    __syncthreads();
  }
  if (t == 0) {
    const float l1 = red[0] + cb2[1];
    const float mm = fmaxf(l0, l1);
    const float lse = mm + logf(__expf(l0 - mm) + __expf(l1 - mm));
    out[b * 2 + 0] = l0 - lse;
    out[b * 2 + 1] = l1 - lse;
  }
}

// ---------------------------------------------------------------------------
extern "C" void kernel_launch(void* const* d_in, const int* in_sizes, int n_in,
                              void* d_out, int out_size, void* d_ws, size_t ws_size,
                              hipStream_t stream) {
  (void)in_sizes; (void)n_in; (void)out_size; (void)ws_size;
  const float* x      = (const float*)d_in[0];
  const float* w0     = (const float*)d_in[2];
  const float* b0     = (const float*)d_in[3];
  const float* c1_mw1 = (const float*)d_in[4];
  const float* c1_mb1 = (const float*)d_in[5];
  const float* c1_mw2 = (const float*)d_in[6];
  const float* c1_mb2 = (const float*)d_in[7];
  const float* c1_gw  = (const float*)d_in[8];
  const float* c1_gb  = (const float*)d_in[9];
  const float* c2_mw1 = (const float*)d_in[10];
  const float* c2_mb1 = (const float*)d_in[11];
  const float* c2_mw2 = (const float*)d_in[12];
  const float* c2_mb2 = (const float*)d_in[13];
  const float* c2_gw  = (const float*)d_in[14];
  const float* c2_gb  = (const float*)d_in[15];
  const float* cw1    = (const float*)d_in[16];
  const float* cb1    = (const float*)d_in[17];
  const float* cw2    = (const float*)d_in[18];
  const float* cb2    = (const float*)d_in[19];

  const size_t NF = (size_t)NTOT * HDIM;  // 8388608 elements
  u16* wsh   = (u16*)d_ws;
  u16* xh_hi = wsh + 0 * NF;
  u16* xh_lo = wsh + 1 * NF;
  u16* x1b   = wsh + 2 * NF;
  u16* x2b   = wsh + 3 * NF;
  u16* a1v   = wsh + 4 * NF;
  u16* a2v   = wsh + 5 * NF;
  u16* uv    = wsh + 6 * NF;
  u16* vv_   = wsh + 7 * NF;
  u16* Wt    = wsh + 8 * NF;                      // 10 * 128*128 u16
  float* sqv = (float*)(Wt + 10 * 128 * 128);     // NTOT fp32
  int* nbrv  = (int*)(sqv + NTOT);                // NTOT*8 int
  // total ~137 MB

  k_prep<<<10, 256, 0, stream>>>(c1_mw1, c1_gw, c2_mw1, c2_gw, c1_mw2, c2_mw2, Wt);
  k_embed<<<2048, 256, 0, stream>>>(x, w0, b0, xh_hi, xh_lo, sqv);
  k_knn<<<512, 256, 0, stream>>>(xh_hi, xh_lo, sqv, nbrv);

  k_ng<<<dim3(512, 4), 256, 0, stream>>>(xh_hi, Wt, c1_mb1, c1_gb,
                                         a1v, a2v, uv, vv_);
  k_conv<<<4096, 256, 0, stream>>>(xh_hi, nbrv, x, a1v, a2v, uv, vv_,
                                   c1_mw1, Wt + 8 * 128 * 128, c1_mb2, c1_gw, x1b);

  k_ng<<<dim3(512, 4), 256, 0, stream>>>(x1b, Wt + 4 * 128 * 128, c2_mb1, c2_gb,
                                         a1v, a2v, uv, vv_);
  k_conv<<<4096, 256, 0, stream>>>(x1b, nbrv, x, a1v, a2v, uv, vv_,
                                   c2_mw1, Wt + 9 * 128 * 128, c2_mb2, c2_gw, x2b);

  k_head<<<64, 256, 0, stream>>>(x1b, x2b, cw1, cb1, cw2, cb2, (float*)d_out);
}

// Round 9
// 711.000 us; speedup vs baseline: 1.5126x; 1.0194x over previous
//
#include <hip/hip_runtime.h>
#include <math.h>
#include <stdint.h>

// Problem constants
#define NTOT   65536
#define NPG    1024
#define KNN    8
#define HDIM   128
#define XSTR   33     // x row stride (32 feat + 1 kf)
#define NEG    0.2f

typedef _Float16 h2 __attribute__((ext_vector_type(2)));
typedef _Float16 h8 __attribute__((ext_vector_type(8)));   // f16x8 MFMA frag
typedef short bf16x8 __attribute__((ext_vector_type(8)));
typedef float f32x4 __attribute__((ext_vector_type(4)));
typedef unsigned short u16;
typedef unsigned int u32;

__device__ __forceinline__ u16 f2bf(float f) {  // RNE float->bf16
  const u32 u = __builtin_bit_cast(u32, f);
  return (u16)((u + 0x7FFFu + ((u >> 16) & 1u)) >> 16);
}
__device__ __forceinline__ float bf2f(u16 h) {
  return __builtin_bit_cast(float, ((u32)h) << 16);
}
__device__ __forceinline__ void bf8_to_f(const u16* __restrict__ p, float* f) {
  const uint4 v = *reinterpret_cast<const uint4*>(p);
  const u32 w[4] = {v.x, v.y, v.z, v.w};
#pragma unroll
  for (int i = 0; i < 4; ++i) {
    f[2 * i]     = bf2f((u16)(w[i] & 0xffffu));
    f[2 * i + 1] = bf2f((u16)(w[i] >> 16));
  }
}

// ---------------------------------------------------------------------------
// K0: xh = relu(feat @ w0 + b0) -> split bf16 (hi, lo); sq[n] = sum(xh^2) fp32
// ---------------------------------------------------------------------------
__global__ __launch_bounds__(256) void k_embed(const float* __restrict__ x,
                                               const float* __restrict__ w0,
                                               const float* __restrict__ b0,
                                               u16* __restrict__ xh_hi,
                                               u16* __restrict__ xh_lo,
                                               float* __restrict__ sq) {
  __shared__ float w0s[32 * HDIM];
  __shared__ float fs[2][32];
  __shared__ float red[256];
  const int tid = threadIdx.x;
  for (int i = tid; i < 32 * HDIM; i += 256) w0s[i] = w0[i];
  const int h = tid & 127;
  const int nl = tid >> 7;
  const float bias = b0[h];
  for (int it = 0; it < 16; ++it) {
    const int n = blockIdx.x * 32 + it * 2 + nl;
    __syncthreads();
    if (tid < 64) {
      const int r = tid >> 5, f = tid & 31;
      fs[r][f] = x[(size_t)(blockIdx.x * 32 + it * 2 + r) * XSTR + f];
    }
    __syncthreads();
    float acc = bias;
#pragma unroll
    for (int f = 0; f < 32; ++f) acc = fmaf(fs[nl][f], w0s[f * HDIM + h], acc);
    acc = fmaxf(acc, 0.f);
    const u16 hh = f2bf(acc);
    xh_hi[(size_t)n * HDIM + h] = hh;
    xh_lo[(size_t)n * HDIM + h] = f2bf(acc - bf2f(hh));
    red[tid] = acc * acc;
    __syncthreads();
    for (int s = 64; s > 0; s >>= 1) {
      if ((tid & 127) < s) red[tid] += red[tid + s];
      __syncthreads();
    }
    if ((tid & 127) == 0) sq[n] = red[tid];
  }
}

// ---------------------------------------------------------------------------
// K-prep: b 0..7: transpose node-GEMM weight blocks to bf16 [n][k].
//          b 8..9: transpose mw2 (layer 1/2) to f16 [h][k].
// grid 10 x 256.
// ---------------------------------------------------------------------------
__global__ __launch_bounds__(256) void k_prep(const float* __restrict__ m1,
                                              const float* __restrict__ g1,
                                              const float* __restrict__ m2,
                                              const float* __restrict__ g2,
                                              const float* __restrict__ w2a,
                                              const float* __restrict__ w2b,
                                              u16* __restrict__ Wt) {
  const int b = blockIdx.x;
  const int t = threadIdx.x;
  const int n = t >> 1, k0 = (t & 1) * 64;
  u16* dst = Wt + (size_t)b * 128 * 128;
  if (b < 8) {
    const int layer = b >> 2, which = b & 3;
    const float* src = (layer == 0) ? ((which < 2) ? m1 : g1)
                                    : ((which < 2) ? m2 : g2);
    src += (size_t)(which & 1) * 128 * HDIM;
    for (int kk = 0; kk < 64; kk += 2) {
      const float f0 = src[(size_t)(k0 + kk) * HDIM + n];
      const float f1 = src[(size_t)(k0 + kk + 1) * HDIM + n];
      const u32 pk = (u32)f2bf(f0) | ((u32)f2bf(f1) << 16);
      *reinterpret_cast<u32*>(&dst[(size_t)n * 128 + k0 + kk]) = pk;
    }
  } else {
    const float* src = (b == 8) ? w2a : w2b;
    for (int kk = 0; kk < 64; kk += 2) {
      const float f0 = src[(size_t)(k0 + kk) * HDIM + n];
      const float f1 = src[(size_t)(k0 + kk + 1) * HDIM + n];
      const u16 h0 = __builtin_bit_cast(u16, (_Float16)f0);
      const u16 h1 = __builtin_bit_cast(u16, (_Float16)f1);
      const u32 pk = (u32)h0 | ((u32)h1 << 16);
      *reinterpret_cast<u32*>(&dst[(size_t)n * 128 + k0 + kk]) = pk;
    }
  }
}

// ---------------------------------------------------------------------------
// K1: per-graph kNN via split-bf16 MFMA (hi*hi + hi*lo + lo*hi, fp32 accum).
// grid 512 (64 graphs x 8 row-blocks of 128), 256 threads = 4 waves.
// ---------------------------------------------------------------------------
__global__ __launch_bounds__(256) void k_knn(const u16* __restrict__ xh_hi,
                                             const u16* __restrict__ xh_lo,
                                             const float* __restrict__ sq,
                                             int* __restrict__ nbr) {
  __shared__ __align__(16) u16 BsH[32 * 128];
  __shared__ __align__(16) u16 BsL[32 * 128];
  __shared__ __align__(16) float Ds[128 * 33];
  __shared__ float sqs[32];
  const int tid = threadIdx.x;
  const int wave = tid >> 6, lane = tid & 63;
  const int fr = lane & 15, fg = lane >> 4;
  const int g = blockIdx.x >> 3;
  const int n0 = (blockIdx.x & 7) * 128;
  const int gbase = g * NPG;

  bf16x8 aH[2][4], aL[2][4];
#pragma unroll
  for (int mt = 0; mt < 2; ++mt)
#pragma unroll
    for (int kt = 0; kt < 4; ++kt) {
      const size_t off =
          (size_t)(gbase + n0 + wave * 32 + mt * 16 + fr) * HDIM + kt * 32 + fg * 8;
      aH[mt][kt] = *reinterpret_cast<const bf16x8*>(&xh_hi[off]);
      aL[mt][kt] = *reinterpret_cast<const bf16x8*>(&xh_lo[off]);
    }

  const int srow = tid >> 1, shalf = tid & 1;
  const int nglob = gbase + n0 + srow;
  float bd[8];
  int bi[8];
#pragma unroll
  for (int i = 0; i < 8; ++i) { bd[i] = 1e30f; bi[i] = 0; }

  char* BsHc = reinterpret_cast<char*>(BsH);
  char* BsLc = reinterpret_cast<char*>(BsL);

  for (int ct = 0; ct < 32; ++ct) {
    const int m0 = gbase + ct * 32;
    __syncthreads();
    if (tid < 32) sqs[tid] = sq[m0 + tid];
    {
      const int col = tid >> 3, kc = (tid & 7) * 16;
      const size_t off = (size_t)(m0 + col) * HDIM + kc;
      const uint4 h0 = *reinterpret_cast<const uint4*>(&xh_hi[off]);
      const uint4 h1 = *reinterpret_cast<const uint4*>(&xh_hi[off + 8]);
      const uint4 l0 = *reinterpret_cast<const uint4*>(&xh_lo[off]);
      const uint4 l1 = *reinterpret_cast<const uint4*>(&xh_lo[off + 8]);
      const int base = col * 256, sw = (col & 7) << 4;
      const int kb = kc * 2;
      *reinterpret_cast<uint4*>(BsHc + base + ((kb) ^ sw)) = h0;
      *reinterpret_cast<uint4*>(BsHc + base + ((kb + 16) ^ sw)) = h1;
      *reinterpret_cast<uint4*>(BsLc + base + ((kb) ^ sw)) = l0;
      *reinterpret_cast<uint4*>(BsLc + base + ((kb + 16) ^ sw)) = l1;
    }
    __syncthreads();
    f32x4 acc[2][2];
#pragma unroll
    for (int mt = 0; mt < 2; ++mt)
#pragma unroll
      for (int nt = 0; nt < 2; ++nt) acc[mt][nt] = (f32x4){0.f, 0.f, 0.f, 0.f};
#pragma unroll
    for (int nt = 0; nt < 2; ++nt) {
      bf16x8 bH[4], bL[4];
      const int col = nt * 16 + fr;
      const int base = col * 256, sw = (col & 7) << 4;
#pragma unroll
      for (int kt = 0; kt < 4; ++kt) {
        const int kb = (kt * 32 + fg * 8) * 2;
        bH[kt] = *reinterpret_cast<const bf16x8*>(BsHc + base + (kb ^ sw));
        bL[kt] = *reinterpret_cast<const bf16x8*>(BsLc + base + (kb ^ sw));
      }
#pragma unroll
      for (int mt = 0; mt < 2; ++mt)
#pragma unroll
        for (int kt = 0; kt < 4; ++kt) {
          acc[mt][nt] = __builtin_amdgcn_mfma_f32_16x16x32_bf16(
              aH[mt][kt], bH[kt], acc[mt][nt], 0, 0, 0);
          acc[mt][nt] = __builtin_amdgcn_mfma_f32_16x16x32_bf16(
              aH[mt][kt], bL[kt], acc[mt][nt], 0, 0, 0);
          acc[mt][nt] = __builtin_amdgcn_mfma_f32_16x16x32_bf16(
              aL[mt][kt], bH[kt], acc[mt][nt], 0, 0, 0);
        }
    }
#pragma unroll
    for (int mt = 0; mt < 2; ++mt)
#pragma unroll
      for (int nt = 0; nt < 2; ++nt)
#pragma unroll
        for (int r = 0; r < 4; ++r)
          Ds[(wave * 32 + mt * 16 + fg * 4 + r) * 33 + nt * 16 + fr] =
              acc[mt][nt][r];
    __syncthreads();
#pragma unroll
    for (int c2 = 0; c2 < 16; ++c2) {
      const int c = shalf * 16 + c2;
      const int m = m0 + c;
      const float d = sqs[c] - 2.f * Ds[srow * 33 + c];
      if ((m != nglob) && (d < bd[7])) {
        bd[7] = d; bi[7] = m;
#pragma unroll
        for (int q = 7; q > 0; --q) {
          if (bd[q] < bd[q - 1]) {
            const float td = bd[q]; bd[q] = bd[q - 1]; bd[q - 1] = td;
            const int ti = bi[q]; bi[q] = bi[q - 1]; bi[q - 1] = ti;
          }
        }
      }
    }
  }
  __syncthreads();
  float* mdist = Ds;
  int* midx = reinterpret_cast<int*>(BsH);
#pragma unroll
  for (int i = 0; i < 8; ++i) { mdist[tid * 8 + i] = bd[i]; midx[tid * 8 + i] = bi[i]; }
  __syncthreads();
  if (shalf == 0) {
    const float* dA = &mdist[(srow * 2) * 8];
    const float* dB = &mdist[(srow * 2 + 1) * 8];
    const int* iA = &midx[(srow * 2) * 8];
    const int* iB = &midx[(srow * 2 + 1) * 8];
    int pa = 0, pb = 0;
    int* outp = &nbr[(size_t)nglob * KNN];
#pragma unroll
    for (int i = 0; i < 8; ++i) {
      const float da = dA[pa], db = dB[pb];
      const bool takeA = (da < db) || ((da == db) && (iA[pa] < iB[pb]));
      outp[i] = takeA ? iA[pa] : iB[pb];
      if (takeA) ++pa; else ++pb;
    }
  }
}

// ---------------------------------------------------------------------------
// K2: node GEMMs via bf16 MFMA. out = xin_b @ W (+bias) -> bf16.
// ---------------------------------------------------------------------------
__global__ __launch_bounds__(256) void k_ng(const u16* __restrict__ xin_b,
                                            const u16* __restrict__ WtL,
                                            const float* __restrict__ mb1,
                                            const float* __restrict__ gb,
                                            u16* __restrict__ a1,
                                            u16* __restrict__ a2,
                                            u16* __restrict__ uu,
                                            u16* __restrict__ vv) {
  const int tid = threadIdx.x;
  const int wave = tid >> 6, lane = tid & 63;
  const int fr = lane & 15, fg = lane >> 4;
  const int n0 = blockIdx.x * 128;
  const int cb = blockIdx.y;
  const u16* W = WtL + (size_t)cb * 128 * 128;
  const float* bias = (cb == 0) ? mb1 : (cb == 2) ? gb : nullptr;
  u16* outp = (cb == 0) ? a1 : (cb == 1) ? a2 : (cb == 2) ? uu : vv;

  bf16x8 afr[2][4];
#pragma unroll
  for (int mt = 0; mt < 2; ++mt)
#pragma unroll
    for (int kt = 0; kt < 4; ++kt)
      afr[mt][kt] = *reinterpret_cast<const bf16x8*>(
          &xin_b[(size_t)(n0 + wave * 32 + mt * 16 + fr) * HDIM + kt * 32 + fg * 8]);

#pragma unroll
  for (int nt = 0; nt < 8; ++nt) {
    const int col = nt * 16 + fr;
    bf16x8 bfr[4];
#pragma unroll
    for (int kt = 0; kt < 4; ++kt)
      bfr[kt] = *reinterpret_cast<const bf16x8*>(&W[(size_t)col * 128 + kt * 32 + fg * 8]);
    const float bv = bias ? bias[col] : 0.f;
#pragma unroll
    for (int mt = 0; mt < 2; ++mt) {
      f32x4 acc = (f32x4){0.f, 0.f, 0.f, 0.f};
#pragma unroll
      for (int kt = 0; kt < 4; ++kt)
        acc = __builtin_amdgcn_mfma_f32_16x16x32_bf16(afr[mt][kt], bfr[kt], acc, 0, 0, 0);
      const int rbase = n0 + wave * 32 + mt * 16 + fg * 4;
#pragma unroll
      for (int r = 0; r < 4; ++r)
        outp[(size_t)(rbase + r) * HDIM + col] = f2bf(acc[r] + bv);
    }
  }
}

// ---------------------------------------------------------------------------
// K3: fused highway edge conv, MFMA edition, occupancy-tuned.
// E built in A-fragment registers; M = E@mw2t^T via mfma_f32_16x16x32_f16,
// staged f16 in LDS (34.8 KB, was 67.6 KB f32) with per-nt acc staging so
// only 8 acc VGPRs are live; __launch_bounds__(256,4) pins VGPR<=128 for
// 4 waves/SIMD. Epilogue identical math to round-5/8 verified path.
// grid 4096 x 256 (4 waves).
// ---------------------------------------------------------------------------
__global__ __launch_bounds__(256, 4) void k_conv(const u16* __restrict__ xin,
                                                 const int* __restrict__ nbr,
                                                 const float* __restrict__ xraw,
                                                 const u16* __restrict__ a1,
                                                 const u16* __restrict__ a2,
                                                 const u16* __restrict__ uu,
                                                 const u16* __restrict__ vv,
                                                 const float* __restrict__ mw1,
                                                 const u16* __restrict__ mw2t,  // f16 [h][k]
                                                 const float* __restrict__ mb2,
                                                 const float* __restrict__ gw,
                                                 u16* __restrict__ xout) {
  __shared__ __align__(16) u16 Msh[128 * 136];   // f16 M, 34816 B
  __shared__ int jn[128];
  __shared__ float fdv[128];
  __shared__ float w1rs[HDIM];
  __shared__ float gwrs[HDIM];
  const int tid = threadIdx.x;
  const int i0 = blockIdx.x * 16;

  if (tid < 128) {
    w1rs[tid] = mw1[256 * HDIM + tid];
    gwrs[tid] = gw[256 * HDIM + tid];
    const int i = i0 + (tid >> 3);
    const int j = nbr[(size_t)i * KNN + (tid & 7)];
    jn[tid] = j;
    fdv[tid] = xraw[(size_t)i * XSTR + 32] - xraw[(size_t)j * XSTR + 32];
  }
  __syncthreads();

  const int wave = tid >> 6, lane = tid & 63;
  const int fr = lane & 15, fg = lane >> 4;

  // Build E fragments: A-operand rows e = wave*32 + mt*16 + fr, k-slice fg*8.
  h8 efrag[2][4];
#pragma unroll
  for (int mt = 0; mt < 2; ++mt) {
    const int e = wave * 32 + mt * 16 + fr;
    const int inode = i0 + (e >> 3);
    const int j = jn[e];
    const float fd = fdv[e];
#pragma unroll
    for (int kt = 0; kt < 4; ++kt) {
      const int k0 = kt * 32 + fg * 8;
      float fa[8], fb[8];
      bf8_to_f(&a1[(size_t)inode * HDIM + k0], fa);
      bf8_to_f(&a2[(size_t)j * HDIM + k0], fb);
      h8 ef;
#pragma unroll
      for (int q = 0; q < 8; ++q)
        ef[q] = (_Float16)fmaxf(fa[q] + fb[q] + fd * w1rs[k0 + q], 0.f);
      efrag[mt][kt] = ef;
    }
  }

  // M = E @ mw2, one nt-column-block at a time; stage each result to LDS
  // immediately so only 2 f32x4 accumulators are ever live.
#pragma unroll
  for (int nt = 0; nt < 8; ++nt) {
    const int col = nt * 16 + fr;
    h8 bfr[4];
#pragma unroll
    for (int kt = 0; kt < 4; ++kt)
      bfr[kt] = *reinterpret_cast<const h8*>(&mw2t[(size_t)col * 128 + kt * 32 + fg * 8]);
#pragma unroll
    for (int mt = 0; mt < 2; ++mt) {
      f32x4 acc = (f32x4){0.f, 0.f, 0.f, 0.f};
#pragma unroll
      for (int kt = 0; kt < 4; ++kt)
        acc = __builtin_amdgcn_mfma_f32_16x16x32_f16(efrag[mt][kt], bfr[kt], acc, 0, 0, 0);
      const int rowb = wave * 32 + mt * 16 + fg * 4;
#pragma unroll
      for (int r = 0; r < 4; ++r)
        Msh[(rowb + r) * 136 + col] = __builtin_bit_cast(u16, (_Float16)acc[r]);
    }
  }
  __syncthreads();

  // epilogue (round-5 verified layout): ty = node-in-block, tx = col-oct
  const int ty = tid >> 4, tx = tid & 15;
  const int node = i0 + ty;
  float xi_[8], ui_[8], mb2v[8], gwv[8];
  {
    bf8_to_f(&xin[(size_t)node * HDIM + tx * 8], xi_);
    bf8_to_f(&uu[(size_t)node * HDIM + tx * 8], ui_);
    const float4 m0 = *reinterpret_cast<const float4*>(&mb2[tx * 8]);
    const float4 m1 = *reinterpret_cast<const float4*>(&mb2[tx * 8 + 4]);
    mb2v[0] = m0.x; mb2v[1] = m0.y; mb2v[2] = m0.z; mb2v[3] = m0.w;
    mb2v[4] = m1.x; mb2v[5] = m1.y; mb2v[6] = m1.z; mb2v[7] = m1.w;
#pragma unroll
    for (int c = 0; c < 8; ++c) gwv[c] = gwrs[tx * 8 + c];
  }
  float msum[8];
#pragma unroll
  for (int c = 0; c < 8; ++c) msum[c] = 0.f;
#pragma unroll
  for (int r = 0; r < 8; ++r) {
    const int e = ty * 8 + r;
    const int j = jn[e];
    const float fd = fdv[e];
    float vj[8], xj[8];
    bf8_to_f(&vv[(size_t)j * HDIM + tx * 8], vj);
    bf8_to_f(&xin[(size_t)j * HDIM + tx * 8], xj);
    const h8 m8 = *reinterpret_cast<const h8*>(&Msh[e * 136 + tx * 8]);
#pragma unroll
    for (int c = 0; c < 8; ++c) {
      const float z = ui_[c] + vj[c] + fd * gwv[c];
      const float gsig = 1.f / (1.f + __expf(-z));
      const float M = (float)m8[c] + mb2v[c];
      msum[c] += gsig * M + (1.f - gsig) * xj[c];
    }
  }
  u32 w[4];
#pragma unroll
  for (int i = 0; i < 4; ++i) {
    float t0 = msum[2 * i] * 0.125f + xi_[2 * i];
    float t1 = msum[2 * i + 1] * 0.125f + xi_[2 * i + 1];
    t0 = (t0 > 0.f) ? t0 : NEG * t0;
    t1 = (t1 > 0.f) ? t1 : NEG * t1;
    w[i] = (u32)f2bf(t0) | ((u32)f2bf(t1) << 16);
  }
  *reinterpret_cast<uint4*>(&xout[(size_t)node * HDIM + tx * 8]) =
      make_uint4(w[0], w[1], w[2], w[3]);
}

// ---------------------------------------------------------------------------
// K4: per-graph max-pool over [x1|x2] (bf16), 2-layer head, log_softmax.
// ---------------------------------------------------------------------------
__global__ __launch_bounds__(256) void k_head(const u16* __restrict__ x1,
                                              const u16* __restrict__ x2,
                                              const float* __restrict__ cw1,
                                              const float* __restrict__ cb1,
                                              const float* __restrict__ cw2,
                                              const float* __restrict__ cb2,
                                              float* __restrict__ out) {
  __shared__ float xc[256];
  __shared__ float hid[128];
  __shared__ float red[128];
  const int b = blockIdx.x, t = threadIdx.x;
  const u16* src = (t < 128) ? x1 : x2;
  const int f = t & 127;
  const size_t base = (size_t)b * NPG;
  float m = -1e30f;
  for (int p = 0; p < NPG; p += 4) {
    const float v0 = bf2f(src[(base + p + 0) * HDIM + f]);
    const float v1 = bf2f(src[(base + p + 1) * HDIM + f]);
    const float v2 = bf2f(src[(base + p + 2) * HDIM + f]);
    const float v3 = bf2f(src[(base + p + 3) * HDIM + f]);
    m = fmaxf(m, fmaxf(fmaxf(v0, v1), fmaxf(v2, v3)));
  }
  xc[t] = m;
  __syncthreads();
  if (t < 128) {
    float acc = cb1[t];
    for (int f2 = 0; f2 < 256; ++f2) acc = fmaf(xc[f2], cw1[f2 * HDIM + t], acc);
    hid[t] = fmaxf(acc, 0.f);
  }
  __syncthreads();
  if (t < 128) red[t] = hid[t] * cw2[t * 2 + 0];
  __syncthreads();
  for (int s = 64; s > 0; s >>= 1) {
    if (t < s) red[t] += red[t + s];
    __syncthreads();
  }
  float l0 = 0.f;
  if (t == 0) l0 = red[0] + cb2[0];
  __syncthreads();
  if (t < 128) red[t] = hid[t] * cw2[t * 2 + 1];
  __syncthreads();
  for (int s = 64; s > 0; s >>= 1) {
    if (t < s) red[t] += red[t + s];
    __syncthreads();
  }
  if (t == 0) {
    const float l1 = red[0] + cb2[1];
    const float mm = fmaxf(l0, l1);
    const float lse = mm + logf(__expf(l0 - mm) + __expf(l1 - mm));
    out[b * 2 + 0] = l0 - lse;
    out[b * 2 + 1] = l1 - lse;
  }
}

// ---------------------------------------------------------------------------
extern "C" void kernel_launch(void* const* d_in, const int* in_sizes, int n_in,
                              void* d_out, int out_size, void* d_ws, size_t ws_size,
                              hipStream_t stream) {
  (void)in_sizes; (void)n_in; (void)out_size; (void)ws_size;
  const float* x      = (const float*)d_in[0];
  const float* w0     = (const float*)d_in[2];
  const float* b0     = (const float*)d_in[3];
  const float* c1_mw1 = (const float*)d_in[4];
  const float* c1_mb1 = (const float*)d_in[5];
  const float* c1_mw2 = (const float*)d_in[6];
  const float* c1_mb2 = (const float*)d_in[7];
  const float* c1_gw  = (const float*)d_in[8];
  const float* c1_gb  = (const float*)d_in[9];
  const float* c2_mw1 = (const float*)d_in[10];
  const float* c2_mb1 = (const float*)d_in[11];
  const float* c2_mw2 = (const float*)d_in[12];
  const float* c2_mb2 = (const float*)d_in[13];
  const float* c2_gw  = (const float*)d_in[14];
  const float* c2_gb  = (const float*)d_in[15];
  const float* cw1    = (const float*)d_in[16];
  const float* cb1    = (const float*)d_in[17];
  const float* cw2    = (const float*)d_in[18];
  const float* cb2    = (const float*)d_in[19];

  const size_t NF = (size_t)NTOT * HDIM;  // 8388608 elements
  u16* wsh   = (u16*)d_ws;
  u16* xh_hi = wsh + 0 * NF;
  u16* xh_lo = wsh + 1 * NF;
  u16* x1b   = wsh + 2 * NF;
  u16* x2b   = wsh + 3 * NF;
  u16* a1v   = wsh + 4 * NF;
  u16* a2v   = wsh + 5 * NF;
  u16* uv    = wsh + 6 * NF;
  u16* vv_   = wsh + 7 * NF;
  u16* Wt    = wsh + 8 * NF;                      // 10 * 128*128 u16
  float* sqv = (float*)(Wt + 10 * 128 * 128);     // NTOT fp32
  int* nbrv  = (int*)(sqv + NTOT);                // NTOT*8 int
  // total ~137 MB

  k_prep<<<10, 256, 0, stream>>>(c1_mw1, c1_gw, c2_mw1, c2_gw, c1_mw2, c2_mw2, Wt);
  k_embed<<<2048, 256, 0, stream>>>(x, w0, b0, xh_hi, xh_lo, sqv);
  k_knn<<<512, 256, 0, stream>>>(xh_hi, xh_lo, sqv, nbrv);

  k_ng<<<dim3(512, 4), 256, 0, stream>>>(xh_hi, Wt, c1_mb1, c1_gb,
                                         a1v, a2v, uv, vv_);
  k_conv<<<4096, 256, 0, stream>>>(xh_hi, nbrv, x, a1v, a2v, uv, vv_,
                                   c1_mw1, Wt + 8 * 128 * 128, c1_mb2, c1_gw, x1b);

  k_ng<<<dim3(512, 4), 256, 0, stream>>>(x1b, Wt + 4 * 128 * 128, c2_mb1, c2_gb,
                                         a1v, a2v, uv, vv_);
  k_conv<<<4096, 256, 0, stream>>>(x1b, nbrv, x, a1v, a2v, uv, vv_,
                                   c2_mw1, Wt + 9 * 128 * 128, c2_mb2, c2_gw, x2b);

  k_head<<<64, 256, 0, stream>>>(x1b, x2b, cw1, cb1, cw2, cb2, (float*)d_out);
}